// Round 17
// baseline (627.509 us; speedup 1.0000x reference)
//
#include <hip/hip_runtime.h>

// ---------------- constants ----------------
#define NN 2048
#define EE 262144

typedef __attribute__((ext_vector_type(8))) short bf16x8;
typedef __attribute__((ext_vector_type(4))) float f32x4;
typedef unsigned int u32;
typedef unsigned short u16;

__device__ __forceinline__ u16 f2bf(float f){
  u32 u = __builtin_bit_cast(u32, f);
  u32 r = u + 0x7FFFu + ((u >> 16) & 1u);
  return (u16)(r >> 16);
}
__device__ __forceinline__ float bf2f(u16 h){
  u32 u = ((u32)h) << 16;
  return __builtin_bit_cast(float, u);
}
__device__ __forceinline__ int swzb(int byte, int row){ return byte ^ ((row & 7) << 4); }
__device__ __forceinline__ float lrelu(float v){ return fmaxf(v, 0.01f * v); }

// ---------------- ws layout (bytes) ----------------
static const size_t WS_WT    = 0;                    // u16 pool (772096 B)
static const size_t WS_EFNN  = 772096;               // u16 E*64
static const size_t WS_ALPHA = WS_EFNN  + 33554432;  // f32 2E ; kvp reuses this after sort
static const size_t WS_H     = WS_ALPHA + 2097152;   // f32 N*96
static const size_t WS_QKV   = WS_H     + 786432;    // f32 N*288 ; P[N][384] spans QKV+OBUF
static const size_t WS_OBUF  = WS_QKV   + 2359296;   // f32 N*96
static const size_t WS_TMPA  = WS_OBUF  + 786432;    // f32 N*96
static const size_t WS_TMPB  = WS_TMPA  + 786432;    // f32 N*192 ; hp[N][192] reuses this
static const size_t WS_X1    = WS_TMPB  + 1572864;   // f32 N*96
static const size_t WS_NUM   = WS_X1    + 786432;    // f32 N*96
static const size_t WS_DEN   = WS_NUM   + 786432;    // f32 N (pad)
static const size_t WS_XS    = WS_DEN   + 8192;      // f32 N*19 (pad)
static const size_t WS_HBF   = WS_XS    + 155648;    // (dead)
static const size_t WS_SIDX  = WS_HBF   + 393216;    // int2 2E
static const size_t WS_ALPS  = WS_SIDX  + 4194304;   // f32 2E (sorted alpha)
static const size_t WS_CNT   = WS_ALPS  + 2097152;   // int N
static const size_t WS_OFFS  = WS_CNT   + 8192;      // int N+1 (pad)
static const size_t WS_PK    = WS_OFFS  + 8192;      // u16 fragment-packed weights (772096 B)

// pool element offsets (bf16, weights transposed [Nc][Kpad])
#define IN1T 0
#define IN2T 3072
#define QKVT 12288
#define OUTT 95232
#define FF1T 122880
#define FF2T 178176
#define EIN1T 233472
#define EIN2T 235520
#define AD1T 239616
#define AR1T 243712
#define GC1T 247808
#define GC2T 321536
#define ENAT 358400
#define ENBT 367616
#define ENCT 376832
#define POOL_TOT 386048

// packed-fragment offsets (u16 elements within pk)
#define PK_EIN1 0
#define PK_EIN2 2048
#define PK_AD1  6144
#define PK_AR1  10240
#define PK_GC2  14336   /* + it*18432 */
#define PK_ENC  51200
#define PK_QKV  60416   /* + l*27648 */
#define PK_OUT  143360  /* + l*9216 */
#define PK_FF1  171008  /* + l*18432 */
#define PK_FF2  226304  /* + l*18432 */
#define PK_IN1  281600
#define PK_IN2  284672
#define PK_GC1  293888  /* + it*36864 ; A|B combined, Nc16=24 */
#define PK_ENAB 367616  /* A|B combined, Nc16=12 */
#define PK_TOT  386048

// ---------------- weight convert (f32 -> bf16, transposed, K-padded) ----------------
struct CvtJobs {
  const float* src[27];
  int K[27], Nc[27], Kp[27];
  int cum[28];
};

__global__ __launch_bounds__(256) void k_cvt(CvtJobs jb, u16* __restrict__ pool){
  int i = blockIdx.x * 256 + threadIdx.x;
  if (i >= jb.cum[27]) return;
  int j = 0;
  while (i >= jb.cum[j + 1]) j++;
  int loc = i - jb.cum[j];
  int Kp = jb.Kp[j];
  int n = loc / Kp, k = loc - n * Kp;
  float v = (k < jb.K[j]) ? jb.src[j][(size_t)k * jb.Nc[j] + n] : 0.f;
  pool[i] = f2bf(v);
}

// repack [Nc][Kp] -> MFMA-fragment lane order: pk[cum + ((ks*Nc16+t16)*64+lane)*8+j]
struct PkJobs {
  int srcOff[27], Nc16[27], Kp[27];
  int cum[28];
};

__global__ __launch_bounds__(256) void k_pack(PkJobs jb, const u16* __restrict__ pool,
                                              u16* __restrict__ pk){
  int i = blockIdx.x * 256 + threadIdx.x;
  if (i >= jb.cum[27]) return;
  int j = 0;
  while (i >= jb.cum[j + 1]) j++;
  int loc = i - jb.cum[j];
  int jj = loc & 7, lane = (loc >> 3) & 63, tk = loc >> 9;
  int Nc16 = jb.Nc16[j];
  int ks = tk / Nc16, t16 = tk - ks * Nc16;
  pk[i] = pool[jb.srcOff[j] + (t16*16 + (lane & 15)) * jb.Kp[j] + ks*32 + (lane >> 4)*8 + jj];
}

__global__ __launch_bounds__(256) void k_xscale(const float* __restrict__ X, const float* __restrict__ ns,
                                                float* __restrict__ xs){
  int i = blockIdx.x * 256 + threadIdx.x;
  if (i < NN * 19) xs[i] = X[i] / ns[i % 19];
}

// ---------------- destination sort (counting sort over 2E edge rows) ----------------
__global__ __launch_bounds__(256) void k_hist(const int* __restrict__ ei, int* __restrict__ cnt){
  int g = blockIdx.x * 256 + threadIdx.x;
  int i1 = (g < EE) ? ei[2*g] : ei[2*(g - EE) + 1];
  atomicAdd(cnt + i1, 1);
}

__global__ __launch_bounds__(256) void k_scan(const int* __restrict__ cnt, int* __restrict__ offs){
  __shared__ int wsum[4], wbase[4];
  int t = threadIdx.x;
  int base = t * 8;
  int c[8]; int T = 0;
  #pragma unroll
  for (int i = 0; i < 8; i++){ c[i] = cnt[base + i]; T += c[i]; }
  int lane = t & 63, wv = t >> 6;
  int inc = T;
  #pragma unroll
  for (int st = 1; st < 64; st <<= 1){
    int v = __shfl_up(inc, st);
    if (lane >= st) inc += v;
  }
  if (lane == 63) wsum[wv] = inc;
  __syncthreads();
  if (t == 0){ int r = 0; for (int w2 = 0; w2 < 4; w2++){ wbase[w2] = r; r += wsum[w2]; } }
  __syncthreads();
  int run = wbase[wv] + inc - T;
  #pragma unroll
  for (int i = 0; i < 8; i++){ offs[base + i] = run; run += c[i]; }
  if (t == 255) offs[2048] = run;
}

__global__ __launch_bounds__(256) void k_scatter(const int* __restrict__ ei, const float* __restrict__ alpha,
    const int* __restrict__ offs, int* __restrict__ rk, int2* __restrict__ sidx, float* __restrict__ alphaS){
  int g = blockIdx.x * 256 + threadIdx.x;
  int i1, i2;
  if (g < EE){ i1 = ei[2*g]; i2 = ei[2*g + 1]; }
  else { int gg = g - EE; i1 = ei[2*gg + 1]; i2 = ei[2*gg]; }
  int r = atomicAdd(rk + i1, 1);
  int pos = offs[i1] + r;
  // NOTE (R15): scattered stores must be cached (L2 write-combining); NT stores
  // here caused 9x HBM write amplification. R16: NT *loads* were also net-negative
  // (re-read data bypasses L2) — keep everything plain cached.
  sidx[pos] = make_int2(i1, i2);
  alphaS[pos] = alpha[g];
}

__global__ __launch_bounds__(256) void k_dens(const int* __restrict__ offs, const float* __restrict__ alphaS,
                                              float* __restrict__ den){
  int n = blockIdx.x * 4 + (threadIdx.x >> 6);
  int lane = threadIdx.x & 63;
  int b = offs[n], e = offs[n + 1];
  float s = 0.f;
  for (int i = b + lane; i < e; i += 64) s += alphaS[i];
  #pragma unroll
  for (int st = 1; st < 64; st <<= 1) s += __shfl_xor(s, st);
  if (lane == 0) den[n] = s + (n == 0 ? 2048.f : 0.f);
}

// ---------------- MFMA tile helper (packed B from L2) ----------------
template<int NT, int KS, int SR, int NC16>
__device__ __forceinline__ void tile_gemm_gp(const char* sm, int aBase, const u16* __restrict__ Wp,
                                             int lane, f32x4* acc){
  const int r15 = lane & 15;
  const int kb = (lane >> 4) * 16;
  #pragma unroll
  for (int ks = 0; ks < KS; ks++){
    bf16x8 a = *(const bf16x8*)(sm + aBase + swzb(r15*SR + ks*64 + kb, r15));
    #pragma unroll
    for (int ct = 0; ct < NT; ct++){
      bf16x8 b = *(const bf16x8*)(Wp + (((size_t)ks*NC16 + ct)*64 + lane)*8);
      acc[ct] = __builtin_amdgcn_mfma_f32_16x16x32_bf16(a, b, acc[ct], 0, 0, 0);
    }
  }
}

// ---------------- gemm v2: 32-row x (2*NT*16)-col tiles, packed B, fused epilogues --------------
// grid (M/32, CB). MODE 0: plain. MODE 1: qkv+kvp pack. MODE 2: LN(R + gemm) (CB=1).
// DIVA 1: A-staging divides by (dden[row] + 1e-8)  (A = num, K = 96).
template<int NT, int KS, int MODE, int ACT, int DIVA = 0>
__global__ __launch_bounds__(256) void k_gemm2(const float* __restrict__ A, int K, int NcTot, int Nc16Tot,
    const u16* __restrict__ pkW, const float* __restrict__ bias, float* __restrict__ C,
    float* __restrict__ C2, const float* __restrict__ R, const float* __restrict__ sc,
    const float* __restrict__ bi, const float* __restrict__ dden)
{
  constexpr int Kpad = KS * 32;
  constexpr int SR = (Kpad*2 + 127) / 128 * 128;
  __shared__ __align__(16) char smem[32*SR + 256];
  const int tid = threadIdx.x;
  const int row0 = blockIdx.x * 32;
  for (int j = tid; j < 32*(Kpad/2); j += 256){
    int r = j / (Kpad/2); int c = (j - r*(Kpad/2)) * 2;
    const float* ap = A + (size_t)(row0 + r)*K + c;
    float f0 = (c < K) ? ap[0] : 0.f;
    float f1 = (c + 1 < K) ? ap[1] : 0.f;
    if (DIVA){
      float dv = 1.f / (dden[row0 + r] + 1e-8f);
      f0 *= dv; f1 *= dv;
    }
    *(u32*)(smem + swzb(r*SR + c*2, r)) = (u32)f2bf(f0) | ((u32)f2bf(f1) << 16);
  }
  __syncthreads();
  const int lane = tid & 63, w = tid >> 6;
  const int wr = w >> 1, wc = w & 1;
  const int r15 = lane & 15;
  const int kb = (lane >> 4) * 16;
  f32x4 acc[NT] = {};
  #pragma unroll
  for (int ks = 0; ks < KS; ks++){
    int row = wr*16 + r15;
    bf16x8 a = *(const bf16x8*)(smem + swzb(row*SR + ks*64 + kb, row));
    #pragma unroll
    for (int ct = 0; ct < NT; ct++){
      int t16g = blockIdx.y*(2*NT) + wc*NT + ct;
      bf16x8 b = *(const bf16x8*)(pkW + (((size_t)ks*Nc16Tot + t16g)*64 + lane)*8);
      acc[ct] = __builtin_amdgcn_mfma_f32_16x16x32_bf16(a, b, acc[ct], 0, 0, 0);
    }
  }
  const int colbase = blockIdx.y*(NT*32) + wc*(NT*16);
  if (MODE != 2){
    #pragma unroll
    for (int ct = 0; ct < NT; ct++){
      int col = colbase + ct*16 + r15;
      float bs = bias ? bias[col] : 0.f;
      #pragma unroll
      for (int q = 0; q < 4; q++){
        int row = row0 + wr*16 + (lane >> 4)*4 + q;
        float v = acc[ct][q] + bs;
        if (ACT == 1) v = lrelu(v);
        if (ACT == 2) v = v > 0.f ? v : 0.f;
        if (MODE == 0){
          C[(size_t)row*NcTot + col] = v;
        } else {
          if (col < 96){
            C[(size_t)row*288 + col] = v;
          } else if (col < 192){
            int hh = (col - 96) >> 3, cc = (col - 96) & 7;
            C2[(((size_t)hh*2048 + row) << 4) + cc] = v;
          } else {
            int hh = (col - 192) >> 3, cc = (col - 192) & 7;
            C2[(((size_t)hh*2048 + row) << 4) + 8 + cc] = v;
          }
        }
      }
    }
  } else {
    // fused residual + LayerNorm over 96 cols (CB=1)
    float* lnb = (float*)(smem + 32*SR);
    float vv[NT][4];
    float ps[4] = {0,0,0,0}, pq[4] = {0,0,0,0};
    #pragma unroll
    for (int ct = 0; ct < NT; ct++){
      int col = colbase + ct*16 + r15;
      float bs = bias[col];
      #pragma unroll
      for (int q = 0; q < 4; q++){
        int row = row0 + wr*16 + (lane >> 4)*4 + q;
        float v = acc[ct][q] + bs + R[(size_t)row*96 + col];
        vv[ct][q] = v;
        ps[q] += v;
        pq[q] += v*v;
      }
    }
    #pragma unroll
    for (int m = 1; m < 16; m <<= 1){
      #pragma unroll
      for (int q = 0; q < 4; q++){
        ps[q] += __shfl_xor(ps[q], m);
        pq[q] += __shfl_xor(pq[q], m);
      }
    }
    if (r15 == 0){
      #pragma unroll
      for (int q = 0; q < 4; q++){
        int row16 = (lane >> 4)*4 + q;
        lnb[(((wr*2 + wc)*16) + row16)*2]     = ps[q];
        lnb[(((wr*2 + wc)*16) + row16)*2 + 1] = pq[q];
      }
    }
    __syncthreads();
    #pragma unroll
    for (int ct = 0; ct < NT; ct++){
      int col = colbase + ct*16 + r15;
      float scv = sc[col], biv = bi[col];
      #pragma unroll
      for (int q = 0; q < 4; q++){
        int row16 = (lane >> 4)*4 + q;
        float s  = lnb[((wr*2)*16 + row16)*2]     + lnb[((wr*2+1)*16 + row16)*2];
        float ss = lnb[((wr*2)*16 + row16)*2 + 1] + lnb[((wr*2+1)*16 + row16)*2 + 1];
        float mean = s * (1.f/96.f);
        float var  = ss * (1.f/96.f) - mean*mean;
        float rs = rsqrtf(var + 1e-5f);
        int row = row0 + wr*16 + row16;
        C[(size_t)row*96 + col] = (vv[ct][q] - mean)*rs*scv + biv;
      }
    }
  }
}

// ---------------- attention v5: (head, 16-row) blocks, LDS-staged keys, shuffle+LDS combine ----------
__global__ __launch_bounds__(256) void k_attn5(const float* __restrict__ qkv, const float* __restrict__ kvp,
                                               float* __restrict__ obuf){
  __shared__ float kbuf[2][4096];
  __shared__ float part[4][16][12];
  const int tid = threadIdx.x;
  const int lane = tid & 63, w = tid >> 6;
  const int r = lane & 15, q = lane >> 4;
  const int head = blockIdx.x >> 7, rb = blockIdx.x & 127;
  const int row = rb*16 + r;
  const float* qp = qkv + (size_t)row*288 + head*8;
  float4 qa = *(const float4*)qp;
  float4 qb = *(const float4*)(qp + 4);
  const float* base = kvp + (size_t)head*32768;
  float4 st0 = *(const float4*)(base + tid*4);
  float4 st1 = *(const float4*)(base + 1024 + tid*4);
  float4 st2 = *(const float4*)(base + 2048 + tid*4);
  float4 st3 = *(const float4*)(base + 3072 + tid*4);
  *(float4*)&kbuf[0][tid*4]        = st0;
  *(float4*)&kbuf[0][1024 + tid*4] = st1;
  *(float4*)&kbuf[0][2048 + tid*4] = st2;
  *(float4*)&kbuf[0][3072 + tid*4] = st3;
  __syncthreads();
  float sm = 0.f;
  float o0=0,o1=0,o2=0,o3=0,o4=0,o5=0,o6=0,o7=0;
  for (int c = 0; c < 8; c++){
    if (c < 7){
      const float* nb = base + (c+1)*4096;
      st0 = *(const float4*)(nb + tid*4);
      st1 = *(const float4*)(nb + 1024 + tid*4);
      st2 = *(const float4*)(nb + 2048 + tid*4);
      st3 = *(const float4*)(nb + 3072 + tid*4);
    }
    const float* kp0 = &kbuf[c & 1][(w*64 + q)*16];
    #pragma unroll
    for (int i = 0; i < 16; i++){
      const float* kp = kp0 + i*64;
      float4 ka = *(const float4*)kp;
      float4 kb4 = *(const float4*)(kp + 4);
      float4 va = *(const float4*)(kp + 8);
      float4 vb = *(const float4*)(kp + 12);
      float s = qa.x*ka.x + qa.y*ka.y + qa.z*ka.z + qa.w*ka.w
              + qb.x*kb4.x + qb.y*kb4.y + qb.z*kb4.z + qb.w*kb4.w;
      s = fminf(s * 0.35355339059327373f, 60.f);
      float p = __expf(s);
      sm += p;
      o0 += p*va.x; o1 += p*va.y; o2 += p*va.z; o3 += p*va.w;
      o4 += p*vb.x; o5 += p*vb.y; o6 += p*vb.z; o7 += p*vb.w;
    }
    if (c < 7){
      float* wb = kbuf[(c+1) & 1];
      *(float4*)&wb[tid*4]        = st0;
      *(float4*)&wb[1024 + tid*4] = st1;
      *(float4*)&wb[2048 + tid*4] = st2;
      *(float4*)&wb[3072 + tid*4] = st3;
      __syncthreads();
    }
  }
  #pragma unroll
  for (int stx = 16; stx < 64; stx <<= 1){
    o0 += __shfl_xor(o0, stx); o1 += __shfl_xor(o1, stx);
    o2 += __shfl_xor(o2, stx); o3 += __shfl_xor(o3, stx);
    o4 += __shfl_xor(o4, stx); o5 += __shfl_xor(o5, stx);
    o6 += __shfl_xor(o6, stx); o7 += __shfl_xor(o7, stx);
    sm += __shfl_xor(sm, stx);
  }
  if (q == 0){
    float* pp = part[w][r];
    pp[0]=o0; pp[1]=o1; pp[2]=o2; pp[3]=o3; pp[4]=o4; pp[5]=o5; pp[6]=o6; pp[7]=o7; pp[8]=sm;
  }
  __syncthreads();
  if (tid < 128){
    int rr = tid >> 3, d = tid & 7;
    float o  = part[0][rr][d] + part[1][rr][d] + part[2][rr][d] + part[3][rr][d];
    float ss = part[0][rr][8] + part[1][rr][8] + part[2][rr][8] + part[3][rr][8];
    obuf[(size_t)(rb*16 + rr)*96 + head*8 + d] = o / ss;
  }
}

// ---------------- fused edge MLPs (packed weights from L2) ----------------
__global__ __launch_bounds__(256) void k_edge(const float* __restrict__ efr, const float* __restrict__ es,
    const u16* __restrict__ pk,
    const float* __restrict__ eb1, const float* __restrict__ eb2,
    const float* __restrict__ adb1, const float* __restrict__ adw2, const float* __restrict__ adb2,
    const float* __restrict__ arb1, const float* __restrict__ arw2, const float* __restrict__ arb2,
    u16* __restrict__ efnn, float* __restrict__ alpha)
{
  __shared__ __align__(16) char smem[16384];
  const int tid = threadIdx.x;
  const int e0 = blockIdx.x * 64;
  for (int j = tid; j < 64*16; j += 256){
    int r = j >> 4; int c = (j & 15) * 2;
    float f0 = 0.f, f1 = 0.f;
    if (c < 12)     f0 = (efr[(size_t)(e0+r)*12 + c]     + 1e-4f) / es[c];
    if (c + 1 < 12) f1 = (efr[(size_t)(e0+r)*12 + c + 1] + 1e-4f) / es[c+1];
    *(u32*)(smem + swzb(r*128 + c*2, r)) = (u32)f2bf(f0) | ((u32)f2bf(f1) << 16);
  }
  __syncthreads();
  const int lane = tid & 63, w = tid >> 6;
  const int r15 = lane & 15;

  auto store_lds = [&](f32x4* acc, int base, const float* bias){
    #pragma unroll
    for (int ct = 0; ct < 4; ct++){
      int col = ct*16 + r15;
      float bs = bias[col];
      #pragma unroll
      for (int q = 0; q < 4; q++){
        int row = w*16 + (lane >> 4)*4 + q;
        *(u16*)(smem + base + swzb(row*128 + col*2, row)) = f2bf(lrelu(acc[ct][q] + bs));
      }
    }
  };

  { f32x4 acc[4] = {};
    tile_gemm_gp<4,1,128,4>(smem, w*2048, pk + PK_EIN1, lane, acc);
    store_lds(acc, 8192, eb1); }
  __syncthreads();
  { f32x4 acc[4] = {};
    tile_gemm_gp<4,2,128,4>(smem, 8192 + w*2048, pk + PK_EIN2, lane, acc);
    store_lds(acc, 0, eb2); }
  __syncthreads();
  for (int j = tid; j < 2048; j += 256){
    int r = j >> 5;
    ((u32*)efnn)[e0*32 + j] = *(const u32*)(smem + swzb(r*128 + (j&31)*4, r));
  }
  { f32x4 acc[4] = {};
    tile_gemm_gp<4,2,128,4>(smem, w*2048, pk + PK_AD1, lane, acc);
    store_lds(acc, 8192, adb1); }
  __syncthreads();
  { int row = tid >> 2, part = tid & 3;
    float s = 0.f;
    #pragma unroll
    for (int i = 0; i < 16; i++){
      int k = part*16 + i;
      s += bf2f(*(const u16*)(smem + 8192 + swzb(row*128 + k*2, row))) * adw2[k];
    }
    s += __shfl_xor(s, 1); s += __shfl_xor(s, 2);
    if (part == 0) alpha[e0 + row] = 1.f / (1.f + __expf(-(s + adb2[0]))); }
  __syncthreads();
  { f32x4 acc[4] = {};
    tile_gemm_gp<4,2,128,4>(smem, w*2048, pk + PK_AR1, lane, acc);
    store_lds(acc, 8192, arb1); }
  __syncthreads();
  { int row = tid >> 2, part = tid & 3;
    float s = 0.f;
    #pragma unroll
    for (int i = 0; i < 16; i++){
      int k = part*16 + i;
      s += bf2f(*(const u16*)(smem + 8192 + swzb(row*128 + k*2, row))) * arw2[k];
    }
    s += __shfl_xor(s, 1); s += __shfl_xor(s, 2);
    if (part == 0) alpha[EE + e0 + row] = 1.f / (1.f + __expf(-(s + arb2[0]))); }
}

// ---------------- graph-conv v9: gc5x body, 4 blocks/node (chunks strided), atomic num ----------
// P[N][384] = [P1|P2] with GC_B1 folded into p1c at init.
__global__ __launch_bounds__(256) void k_gc9(const float* __restrict__ P,
    const int2* __restrict__ sidx, const float* __restrict__ alphaS, const int* __restrict__ offs,
    const u16* __restrict__ wt2p, const float* __restrict__ b1, const float* __restrict__ b2,
    float* __restrict__ num)
{
  __shared__ __align__(16) char smem[26624];
  float* p1c  = (float*)(smem + 24576);
  int*   i2b  = (int*)  (smem + 25344);
  float* alph = (float*)(smem + 25600);
  float* part = (float*)(smem + 25856);
  const int tid = threadIdx.x;
  const int lane = tid & 63, w = tid >> 6;
  const int wr = w >> 1, wc = w & 1;
  const int r15 = lane & 15;
  const int kb = (lane >> 4) * 16;
  const int n = blockIdx.x >> 2, sp = blockIdx.x & 3;
  const int rbeg = offs[n], rend = offs[n + 1];
  const int total = rend - rbeg + (n == 0 ? 1 : 0);   // node 0: +1 virtual row
  const int nch = (total + 63) >> 6;
  if (sp >= nch) return;                               // load-balance early exit
  if (tid < 192) p1c[tid] = P[(size_t)n*384 + tid] + b1[tid];
  float b2r[3];
  #pragma unroll
  for (int ct = 0; ct < 3; ct++) b2r[ct] = b2[wc*48 + ct*16 + r15];
  float cs0 = 0.f, cs1 = 0.f, cs2 = 0.f;

  int pm_i2 = 0; float pm_al = 0.f;
  auto fetch_meta = [&](int c){
    if (tid < 64){
      int pos = rbeg + c*64 + tid;
      if (pos < rend){
        pm_i2 = sidx[pos].y;
        pm_al = alphaS[pos];
      } else if (n == 0 && pos == rend){ pm_i2 = 0; pm_al = 2048.f; }
      else { pm_i2 = 0; pm_al = 0.f; }
    }
  };
  fetch_meta(sp);
  __syncthreads();   // p1c visible
  for (int c = sp; c < nch; c += 4){
    if (tid < 64){ i2b[tid] = pm_i2; alph[tid] = pm_al; }
    __syncthreads();
    for (int j = tid; j < 1536; j += 256){
      int r = j / 24, q = j - (j/24)*24;
      int c8 = q * 8;
      const float* p2 = P + (size_t)i2b[r]*384 + 192 + c8;
      float4 b0 = *(const float4*)p2, b1v = *(const float4*)(p2 + 4);
      const float* pc = p1c + c8;
      u16 pkv[8];
      pkv[0]=f2bf(lrelu(pc[0]+b0.x)); pkv[1]=f2bf(lrelu(pc[1]+b0.y));
      pkv[2]=f2bf(lrelu(pc[2]+b0.z)); pkv[3]=f2bf(lrelu(pc[3]+b0.w));
      pkv[4]=f2bf(lrelu(pc[4]+b1v.x)); pkv[5]=f2bf(lrelu(pc[5]+b1v.y));
      pkv[6]=f2bf(lrelu(pc[6]+b1v.z)); pkv[7]=f2bf(lrelu(pc[7]+b1v.w));
      *(bf16x8*)(smem + swzb(r*384 + c8*2, r)) = *(bf16x8*)pkv;
    }
    __syncthreads();
    float ar[2][4];
    #pragma unroll
    for (int rt = 0; rt < 2; rt++)
      #pragma unroll
      for (int q = 0; q < 4; q++)
        ar[rt][q] = alph[wr*32 + rt*16 + (lane >> 4)*4 + q];
    if (c + 4 < nch) fetch_meta(c + 4);        // overlaps MFMA below
    f32x4 acc2[2][3] = {};
    #pragma unroll
    for (int ks = 0; ks < 6; ks++){
      bf16x8 a[2];
      #pragma unroll
      for (int rt = 0; rt < 2; rt++){
        int row = wr*32 + rt*16 + r15;
        a[rt] = *(const bf16x8*)(smem + swzb(row*384 + ks*64 + kb, row));
      }
      #pragma unroll
      for (int ct = 0; ct < 3; ct++){
        bf16x8 b = *(const bf16x8*)(wt2p + (((size_t)ks*6 + wc*3 + ct)*64 + lane)*8);
        #pragma unroll
        for (int rt = 0; rt < 2; rt++)
          acc2[rt][ct] = __builtin_amdgcn_mfma_f32_16x16x32_bf16(a[rt], b, acc2[rt][ct], 0, 0, 0);
      }
    }
    #pragma unroll
    for (int rt = 0; rt < 2; rt++){
      #pragma unroll
      for (int q = 0; q < 4; q++){
        float aw = ar[rt][q];
        cs0 += aw * lrelu(acc2[rt][0][q] + b2r[0]);
        cs1 += aw * lrelu(acc2[rt][1][q] + b2r[1]);
        cs2 += aw * lrelu(acc2[rt][2][q] + b2r[2]);
      }
    }
    __syncthreads();
  }
  #pragma unroll
  for (int stx = 16; stx < 64; stx <<= 1){
    cs0 += __shfl_xor(cs0, stx);
    cs1 += __shfl_xor(cs1, stx);
    cs2 += __shfl_xor(cs2, stx);
  }
  if (lane < 16){
    part[(w*3 + 0)*16 + lane] = cs0;
    part[(w*3 + 1)*16 + lane] = cs1;
    part[(w*3 + 2)*16 + lane] = cs2;
  }
  __syncthreads();
  if (tid < 96){
    int wc2 = tid / 48, rem = tid - wc2*48;
    int ct = rem / 16, rr = rem - ct*16;
    float tot = part[(wc2*3 + ct)*16 + rr] + part[((2 + wc2)*3 + ct)*16 + rr];
    atomicAdd(num + (size_t)n*96 + tid, tot);
  }
}

// ---------------- final predictor v3: hp[N][192] combined, EN_B1 here ----------------
__global__ __launch_bounds__(256) void k_final3(const float* __restrict__ hp,
    const int* __restrict__ ei, const u16* __restrict__ efnn, const float* __restrict__ efr,
    const float* __restrict__ es, const u16* __restrict__ encp, const float* __restrict__ enb1,
    const float* __restrict__ enw2, const float* __restrict__ enb2, float* __restrict__ out)
{
  __shared__ __align__(16) char smem[38400];
  float* etb = (float*)(smem + 12288);
  float* w2s = (float*)(smem + 37120);
  float* b1s = (float*)(smem + 37504);
  int*   eix = (int*)  (smem + 37888);
  const int tid = threadIdx.x;
  const int e0 = blockIdx.x * 64;
  for (int j = tid; j < 768; j += 256){
    int r = j / 12, q = j - (j/12)*12;
    int e = e0 + r;
    bf16x8 v;
    if (q < 8){
      v = *(const bf16x8*)(efnn + (size_t)e*64 + q*8);
    } else if (q < 10){
      u16 pkv[8];
      #pragma unroll
      for (int i = 0; i < 8; i++){
        int cc = (q - 8)*8 + i;
        pkv[i] = (cc < 12) ? f2bf((efr[(size_t)e*12 + cc] + 1e-4f) / es[cc]) : (u16)0;
      }
      v = *(bf16x8*)pkv;
    } else {
      v = bf16x8{0,0,0,0,0,0,0,0};
    }
    *(bf16x8*)(smem + swzb(r*192 + q*16, r)) = v;
  }
  if (tid < 96) w2s[tid] = enw2[tid];
  else if (tid < 192) b1s[tid - 96] = enb1[tid - 96];
  if (tid < 64){ eix[2*tid] = ei[2*(e0+tid)]; eix[2*tid+1] = ei[2*(e0+tid)+1]; }
  __syncthreads();
  const int lane = tid & 63, w = tid >> 6;
  const int r15 = lane & 15;
  f32x4 acc[6] = {};
  tile_gemm_gp<6,3,192,6>(smem, w*16*192, encp, lane, acc);
  #pragma unroll
  for (int ct = 0; ct < 6; ct++){
    int col = ct*16 + r15;
    #pragma unroll
    for (int q = 0; q < 4; q++){
      int row = w*16 + (lane >> 4)*4 + q;
      etb[row*97 + col] = acc[ct][q];
    }
  }
  __syncthreads();
  int r = tid >> 2, part = tid & 3;
  int s1 = eix[2*r], s2 = eix[2*r + 1];
  const float* p1 = hp + (size_t)s1*192 + part*24;
  const float* p2 = hp + (size_t)s2*192 + 96 + part*24;
  const float* et = etb + r*97 + part*24;
  const float* wz = w2s + part*24;
  const float* bz = b1s + part*24;
  float s = 0.f;
  #pragma unroll
  for (int i = 0; i < 24; i++){
    float v = et[i] + p1[i] + p2[i] + bz[i];
    s += lrelu(v) * wz[i];
  }
  s += __shfl_xor(s, 1); s += __shfl_xor(s, 2);
  if (part == 0) out[e0 + r] = 1.f / (1.f + __expf(-(s + enb2[0])));
}

// ---------------- host ----------------
extern "C" void kernel_launch(void* const* d_in, const int* in_sizes, int n_in,
                              void* d_out, int out_size, void* d_ws, size_t ws_size,
                              hipStream_t stream) {
  (void)in_sizes; (void)n_in; (void)out_size; (void)ws_size;
  const float* X      = (const float*)d_in[0];
  const float* EFR    = (const float*)d_in[1];
  const int*   EI     = (const int*)  d_in[2];
  const float* NS     = (const float*)d_in[3];
  const float* ES     = (const float*)d_in[4];
  const float* IN_W1  = (const float*)d_in[5];
  const float* IN_B1  = (const float*)d_in[6];
  const float* IN_W2  = (const float*)d_in[7];
  const float* IN_B2  = (const float*)d_in[8];
  const float* QKV_W  = (const float*)d_in[9];
  const float* QKV_B  = (const float*)d_in[10];
  const float* OUT_W  = (const float*)d_in[11];
  const float* OUT_B  = (const float*)d_in[12];
  const float* LN1S   = (const float*)d_in[13];
  const float* LN1B   = (const float*)d_in[14];
  const float* FFW1   = (const float*)d_in[15];
  const float* FFB1   = (const float*)d_in[16];
  const float* FFW2   = (const float*)d_in[17];
  const float* FFB2   = (const float*)d_in[18];
  const float* LN2S   = (const float*)d_in[19];
  const float* LN2B   = (const float*)d_in[20];
  const float* EIN_W1 = (const float*)d_in[21];
  const float* EIN_B1 = (const float*)d_in[22];
  const float* EIN_W2 = (const float*)d_in[23];
  const float* EIN_B2 = (const float*)d_in[24];
  const float* AD_W1  = (const float*)d_in[25];
  const float* AD_B1  = (const float*)d_in[26];
  const float* AD_W2  = (const float*)d_in[27];
  const float* AD_B2  = (const float*)d_in[28];
  const float* AR_W1  = (const float*)d_in[29];
  const float* AR_B1  = (const float*)d_in[30];
  const float* AR_W2  = (const float*)d_in[31];
  const float* AR_B2  = (const float*)d_in[32];
  const float* GC_W1  = (const float*)d_in[33];
  const float* GC_B1  = (const float*)d_in[34];
  const float* GC_W2  = (const float*)d_in[35];
  const float* GC_B2  = (const float*)d_in[36];
  const float* EN_W1  = (const float*)d_in[37];
  const float* EN_B1  = (const float*)d_in[38];
  const float* EN_W2  = (const float*)d_in[39];
  const float* EN_B2  = (const float*)d_in[40];

  char* ws = (char*)d_ws;
  u16*   pool   = (u16*)  (ws + WS_WT);
  u16*   efnn   = (u16*)  (ws + WS_EFNN);
  float* alpha  = (float*)(ws + WS_ALPHA);
  float* h      = (float*)(ws + WS_H);
  float* qkvb   = (float*)(ws + WS_QKV);
  float* obuf   = (float*)(ws + WS_OBUF);
  float* tmpA   = (float*)(ws + WS_TMPA);
  float* tmpB   = (float*)(ws + WS_TMPB);
  float* x1     = (float*)(ws + WS_X1);
  float* num    = (float*)(ws + WS_NUM);
  float* den    = (float*)(ws + WS_DEN);
  float* xs     = (float*)(ws + WS_XS);
  int2*  sidx   = (int2*) (ws + WS_SIDX);
  float* alphaS = (float*)(ws + WS_ALPS);
  int*   cnt    = (int*)  (ws + WS_CNT);
  int*   offs   = (int*)  (ws + WS_OFFS);
  u16*   pk     = (u16*)  (ws + WS_PK);
  float* P      = (float*)(ws + WS_QKV);   // [N][384], spans QKV+OBUF (dead after encoder)
  float* hp     = (float*)(ws + WS_TMPB);  // [N][192]
  float* kvp    = (float*)(ws + WS_ALPHA); // reuse: alpha dead after k_scatter

  // ---- weight conversion jobs ----
  CvtJobs jb;
  int idx = 0, cum = 0;
  auto addjob = [&](const float* s, int K, int Nc, int Kp){
    jb.src[idx] = s; jb.K[idx] = K; jb.Nc[idx] = Nc; jb.Kp[idx] = Kp;
    jb.cum[idx] = cum; cum += Nc * Kp; idx++;
  };
  addjob(IN_W1, 19, 96, 32);
  addjob(IN_W2, 96, 96, 96);
  for (int l = 0; l < 3; l++) addjob(QKV_W + (size_t)l*96*288, 96, 288, 96);
  for (int l = 0; l < 3; l++) addjob(OUT_W + (size_t)l*96*96,  96, 96,  96);
  for (int l = 0; l < 3; l++) addjob(FFW1  + (size_t)l*96*192, 96, 192, 96);
  for (int l = 0; l < 3; l++) addjob(FFW2  + (size_t)l*192*96, 192, 96, 192);
  addjob(EIN_W1, 12, 64, 32);
  addjob(EIN_W2, 64, 64, 64);
  addjob(AD_W1,  64, 64, 64);
  addjob(AR_W1,  64, 64, 64);
  for (int i = 0; i < 2; i++){
    addjob(GC_W1 + (size_t)i*192*192,          96, 192, 96);
    addjob(GC_W1 + (size_t)i*192*192 + 96*192, 96, 192, 96);
  }
  for (int i = 0; i < 2; i++) addjob(GC_W2 + (size_t)i*192*96, 192, 96, 192);
  addjob(EN_W1,            96, 96, 96);
  addjob(EN_W1 + 96*96,    96, 96, 96);
  addjob(EN_W1 + 192*96,   76, 96, 96);
  jb.cum[idx] = cum;

  k_cvt<<<(POOL_TOT + 255)/256, 256, 0, stream>>>(jb, pool);

  // ---- fragment packing jobs; ORDER MUST MATCH PK_* offsets ----
  PkJobs pj;
  int pidx = 0, pcum = 0;
  auto addpk = [&](int srcOff, int Nc16, int Ks, int Kp){
    pj.srcOff[pidx] = srcOff; pj.Nc16[pidx] = Nc16; pj.Kp[pidx] = Kp;
    pj.cum[pidx] = pcum; pcum += Nc16 * Ks * 512; pidx++;
  };
  addpk(EIN1T, 4, 1, 32);
  addpk(EIN2T, 4, 2, 64);
  addpk(AD1T,  4, 2, 64);
  addpk(AR1T,  4, 2, 64);
  addpk(GC2T,          6, 6, 192);
  addpk(GC2T + 18432,  6, 6, 192);
  addpk(ENCT, 6, 3, 96);
  for (int l = 0; l < 3; l++) addpk(QKVT + l*27648, 18, 3, 96);
  for (int l = 0; l < 3; l++) addpk(OUTT + l*9216,   6, 3, 96);
  for (int l = 0; l < 3; l++) addpk(FF1T + l*18432, 12, 3, 96);
  for (int l = 0; l < 3; l++) addpk(FF2T + l*18432,  6, 6, 192);
  addpk(IN1T, 6, 1, 32);
  addpk(IN2T, 6, 3, 96);
  for (int i = 0; i < 2; i++) addpk(GC1T + i*36864, 24, 3, 96);   // A|B combined
  addpk(ENAT, 12, 3, 96);                                        // ENA|ENB combined
  for (int z = pidx; z <= 27; z++) pj.cum[z] = pcum;              // == PK_TOT

  k_pack<<<(PK_TOT + 255)/256, 256, 0, stream>>>(pj, pool, pk);

  // ---- node embedding ----
  k_xscale<<<(NN*19 + 255)/256, 256, 0, stream>>>(X, NS, xs);
  k_gemm2<3,1,0,1><<<dim3(64,1), 256, 0, stream>>>(xs, 19, 96, 6, pk + PK_IN1, IN_B1, tmpA,
                                                   nullptr, nullptr, nullptr, nullptr, nullptr);
  k_gemm2<3,3,0,1><<<dim3(64,1), 256, 0, stream>>>(tmpA, 96, 96, 6, pk + PK_IN2, IN_B2, h,
                                                   nullptr, nullptr, nullptr, nullptr, nullptr);

  // ---- edge MLPs + attention weights ----
  k_edge<<<EE/64, 256, 0, stream>>>(EFR, ES, pk, EIN_B1, EIN_B2,
                                    AD_B1, AD_W2, AD_B2, AR_B1, AR_W2, AR_B2, efnn, alpha);

  // ---- destination sort + den ----
  (void)hipMemsetAsync(cnt, 0, NN*4, stream);
  k_hist<<<(2*EE)/256, 256, 0, stream>>>(EI, cnt);
  k_scan<<<1, 256, 0, stream>>>(cnt, offs);
  (void)hipMemsetAsync(cnt, 0, NN*4, stream);
  k_scatter<<<(2*EE)/256, 256, 0, stream>>>(EI, alpha, offs, cnt, sidx, alphaS);
  k_dens<<<NN/4, 256, 0, stream>>>(offs, alphaS, den);

  // ---- 3 encoder layers (5 launches each) ----
  for (int l = 0; l < 3; l++){
    k_gemm2<3,3,1,0><<<dim3(64,3), 256, 0, stream>>>(h, 96, 288, 18, pk + PK_QKV + l*27648,
                                                     QKV_B + l*288, qkvb, kvp, nullptr, nullptr, nullptr, nullptr);
    k_attn5<<<1536, 256, 0, stream>>>(qkvb, kvp, obuf);
    k_gemm2<3,3,2,0><<<dim3(64,1), 256, 0, stream>>>(obuf, 96, 96, 6, pk + PK_OUT + l*9216,
                                                     OUT_B + l*96, x1, nullptr, h, LN1S + l*96, LN1B + l*96, nullptr);
    k_gemm2<3,3,0,2><<<dim3(64,2), 256, 0, stream>>>(x1, 96, 192, 12, pk + PK_FF1 + l*18432,
                                                     FFB1 + l*192, tmpB, nullptr, nullptr, nullptr, nullptr, nullptr);
    k_gemm2<3,6,2,0><<<dim3(64,1), 256, 0, stream>>>(tmpB, 192, 96, 6, pk + PK_FF2 + l*18432,
                                                     FFB2 + l*96, h, nullptr, x1, LN2S + l*96, LN2B + l*96, nullptr);
  }

  // ---- 2 graph-conv iterations: P = [h@W1a | h@W1b] (one gemm), 4-way split gc, atomic num ----
  for (int it = 0; it < 2; it++){
    if (it == 0){
      k_gemm2<3,3,0,0><<<dim3(64,3), 256, 0, stream>>>(h, 96, 384, 24, pk + PK_GC1 + it*36864,
                                                       nullptr, P, nullptr, nullptr, nullptr, nullptr, nullptr);
    } else {
      k_gemm2<3,3,0,0,1><<<dim3(64,3), 256, 0, stream>>>(num, 96, 384, 24, pk + PK_GC1 + it*36864,
                                                         nullptr, P, nullptr, nullptr, nullptr, nullptr, den);
    }
    (void)hipMemsetAsync(num, 0, NN*96*4, stream);
    k_gc9<<<4*NN, 256, 0, stream>>>(P, sidx, alphaS, offs,
                                    pk + PK_GC2 + it*18432, GC_B1 + it*192, GC_B2 + it*96, num);
  }

  // ---- final predictor: hp = [num/den @ ENA | @ ENB] (one gemm, no bias) ----
  k_gemm2<3,3,0,0,1><<<dim3(64,2), 256, 0, stream>>>(num, 96, 192, 12, pk + PK_ENAB,
                                                     nullptr, hp, nullptr, nullptr, nullptr, nullptr, den);
  k_final3<<<EE/64, 256, 0, stream>>>(hp, EI, efnn, EFR, ES,
                                      pk + PK_ENC, EN_B1, EN_W2, EN_B2, (float*)d_out);
}

// Round 18
// 589.500 us; speedup vs baseline: 1.0645x; 1.0645x over previous
//
#include <hip/hip_runtime.h>

// ---------------- constants ----------------
#define NN 2048
#define EE 262144

typedef __attribute__((ext_vector_type(8))) short bf16x8;
typedef __attribute__((ext_vector_type(4))) float f32x4;
typedef unsigned int u32;
typedef unsigned short u16;

__device__ __forceinline__ u16 f2bf(float f){
  u32 u = __builtin_bit_cast(u32, f);
  u32 r = u + 0x7FFFu + ((u >> 16) & 1u);
  return (u16)(r >> 16);
}
__device__ __forceinline__ float bf2f(u16 h){
  u32 u = ((u32)h) << 16;
  return __builtin_bit_cast(float, u);
}
__device__ __forceinline__ int swzb(int byte, int row){ return byte ^ ((row & 7) << 4); }
__device__ __forceinline__ float lrelu(float v){ return fmaxf(v, 0.01f * v); }

// ---------------- ws layout (bytes) ----------------
static const size_t WS_WT    = 0;                    // u16 pool (772096 B)
static const size_t WS_EFNN  = 772096;               // u16 E*64
static const size_t WS_ALPHA = WS_EFNN  + 33554432;  // f32 2E ; kvp reuses this after sort
static const size_t WS_H     = WS_ALPHA + 2097152;   // f32 N*96
static const size_t WS_QKV   = WS_H     + 786432;    // f32 N*288 ; P[N][384] spans QKV+OBUF
static const size_t WS_OBUF  = WS_QKV   + 2359296;   // f32 N*96
static const size_t WS_TMPA  = WS_OBUF  + 786432;    // f32 N*96
static const size_t WS_TMPB  = WS_TMPA  + 786432;    // f32 N*192 ; hp[N][192] reuses this
static const size_t WS_X1    = WS_TMPB  + 1572864;   // f32 N*96
static const size_t WS_NUM   = WS_X1    + 786432;    // f32 N*96
static const size_t WS_DEN   = WS_NUM   + 786432;    // f32 N (pad)
static const size_t WS_XS    = WS_DEN   + 8192;      // f32 N*19 (pad)
static const size_t WS_HBF   = WS_XS    + 155648;    // (dead)
static const size_t WS_SIDX  = WS_HBF   + 393216;    // int2 2E
static const size_t WS_ALPS  = WS_SIDX  + 4194304;   // f32 2E (sorted alpha)
static const size_t WS_CNT   = WS_ALPS  + 2097152;   // int N
static const size_t WS_OFFS  = WS_CNT   + 8192;      // int N+1 (pad)
static const size_t WS_PK    = WS_OFFS  + 8192;      // u16 fragment-packed weights (772096 B)

// pool element offsets (bf16, weights transposed [Nc][Kpad])
#define IN1T 0
#define IN2T 3072
#define QKVT 12288
#define OUTT 95232
#define FF1T 122880
#define FF2T 178176
#define EIN1T 233472
#define EIN2T 235520
#define AD1T 239616
#define AR1T 243712
#define GC1T 247808
#define GC2T 321536
#define ENAT 358400
#define ENBT 367616
#define ENCT 376832
#define POOL_TOT 386048

// packed-fragment offsets (u16 elements within pk)
#define PK_EIN1 0
#define PK_EIN2 2048
#define PK_AD1  6144
#define PK_AR1  10240
#define PK_GC2  14336   /* + it*18432 */
#define PK_ENC  51200
#define PK_QKV  60416   /* + l*27648 */
#define PK_OUT  143360  /* + l*9216 */
#define PK_FF1  171008  /* + l*18432 */
#define PK_FF2  226304  /* + l*18432 */
#define PK_IN1  281600
#define PK_IN2  284672
#define PK_GC1  293888  /* + it*36864 ; A|B combined, Nc16=24 */
#define PK_ENAB 367616  /* A|B combined, Nc16=12 */
#define PK_TOT  386048

// ---------------- weight convert (f32 -> bf16, transposed, K-padded) ----------------
struct CvtJobs {
  const float* src[27];
  int K[27], Nc[27], Kp[27];
  int cum[28];
};

__global__ __launch_bounds__(256) void k_cvt(CvtJobs jb, u16* __restrict__ pool){
  int i = blockIdx.x * 256 + threadIdx.x;
  if (i >= jb.cum[27]) return;
  int j = 0;
  while (i >= jb.cum[j + 1]) j++;
  int loc = i - jb.cum[j];
  int Kp = jb.Kp[j];
  int n = loc / Kp, k = loc - n * Kp;
  float v = (k < jb.K[j]) ? jb.src[j][(size_t)k * jb.Nc[j] + n] : 0.f;
  pool[i] = f2bf(v);
}

// repack [Nc][Kp] -> MFMA-fragment lane order: pk[cum + ((ks*Nc16+t16)*64+lane)*8+j]
struct PkJobs {
  int srcOff[27], Nc16[27], Kp[27];
  int cum[28];
};

__global__ __launch_bounds__(256) void k_pack(PkJobs jb, const u16* __restrict__ pool,
                                              u16* __restrict__ pk){
  int i = blockIdx.x * 256 + threadIdx.x;
  if (i >= jb.cum[27]) return;
  int j = 0;
  while (i >= jb.cum[j + 1]) j++;
  int loc = i - jb.cum[j];
  int jj = loc & 7, lane = (loc >> 3) & 63, tk = loc >> 9;
  int Nc16 = jb.Nc16[j];
  int ks = tk / Nc16, t16 = tk - ks * Nc16;
  pk[i] = pool[jb.srcOff[j] + (t16*16 + (lane & 15)) * jb.Kp[j] + ks*32 + (lane >> 4)*8 + jj];
}

__global__ __launch_bounds__(256) void k_xscale(const float* __restrict__ X, const float* __restrict__ ns,
                                                float* __restrict__ xs){
  int i = blockIdx.x * 256 + threadIdx.x;
  if (i < NN * 19) xs[i] = X[i] / ns[i % 19];
}

// ---------------- destination sort (counting sort over 2E edge rows) ----------------
__global__ __launch_bounds__(256) void k_hist(const int* __restrict__ ei, int* __restrict__ cnt){
  int g = blockIdx.x * 256 + threadIdx.x;
  int i1 = (g < EE) ? ei[2*g] : ei[2*(g - EE) + 1];
  atomicAdd(cnt + i1, 1);
}

__global__ __launch_bounds__(256) void k_scan(const int* __restrict__ cnt, int* __restrict__ offs){
  __shared__ int wsum[4], wbase[4];
  int t = threadIdx.x;
  int base = t * 8;
  int c[8]; int T = 0;
  #pragma unroll
  for (int i = 0; i < 8; i++){ c[i] = cnt[base + i]; T += c[i]; }
  int lane = t & 63, wv = t >> 6;
  int inc = T;
  #pragma unroll
  for (int st = 1; st < 64; st <<= 1){
    int v = __shfl_up(inc, st);
    if (lane >= st) inc += v;
  }
  if (lane == 63) wsum[wv] = inc;
  __syncthreads();
  if (t == 0){ int r = 0; for (int w2 = 0; w2 < 4; w2++){ wbase[w2] = r; r += wsum[w2]; } }
  __syncthreads();
  int run = wbase[wv] + inc - T;
  #pragma unroll
  for (int i = 0; i < 8; i++){ offs[base + i] = run; run += c[i]; }
  if (t == 255) offs[2048] = run;
}

__global__ __launch_bounds__(256) void k_scatter(const int* __restrict__ ei, const float* __restrict__ alpha,
    const int* __restrict__ offs, int* __restrict__ rk, int2* __restrict__ sidx, float* __restrict__ alphaS){
  int g = blockIdx.x * 256 + threadIdx.x;
  int i1, i2;
  if (g < EE){ i1 = ei[2*g]; i2 = ei[2*g + 1]; }
  else { int gg = g - EE; i1 = ei[2*gg + 1]; i2 = ei[2*gg]; }
  int r = atomicAdd(rk + i1, 1);
  int pos = offs[i1] + r;
  // NOTE (R15/R16): keep ALL memory ops plain cached. NT stores on scatters gave
  // 9x HBM write amplification; NT loads bypassed L2 for re-read data (net loss).
  sidx[pos] = make_int2(i1, i2);
  alphaS[pos] = alpha[g];
}

__global__ __launch_bounds__(256) void k_dens(const int* __restrict__ offs, const float* __restrict__ alphaS,
                                              float* __restrict__ den){
  int n = blockIdx.x * 4 + (threadIdx.x >> 6);
  int lane = threadIdx.x & 63;
  int b = offs[n], e = offs[n + 1];
  float s = 0.f;
  for (int i = b + lane; i < e; i += 64) s += alphaS[i];
  #pragma unroll
  for (int st = 1; st < 64; st <<= 1) s += __shfl_xor(s, st);
  if (lane == 0) den[n] = s + (n == 0 ? 2048.f : 0.f);
}

// ---------------- MFMA tile helper (packed B from L2) ----------------
template<int NT, int KS, int SR, int NC16>
__device__ __forceinline__ void tile_gemm_gp(const char* sm, int aBase, const u16* __restrict__ Wp,
                                             int lane, f32x4* acc){
  const int r15 = lane & 15;
  const int kb = (lane >> 4) * 16;
  #pragma unroll
  for (int ks = 0; ks < KS; ks++){
    bf16x8 a = *(const bf16x8*)(sm + aBase + swzb(r15*SR + ks*64 + kb, r15));
    #pragma unroll
    for (int ct = 0; ct < NT; ct++){
      bf16x8 b = *(const bf16x8*)(Wp + (((size_t)ks*NC16 + ct)*64 + lane)*8);
      acc[ct] = __builtin_amdgcn_mfma_f32_16x16x32_bf16(a, b, acc[ct], 0, 0, 0);
    }
  }
}

// ---------------- gemm v2: 32-row x (2*NT*16)-col tiles, packed B, fused epilogues --------------
// grid (M/32, CB). MODE 0: plain. MODE 1: qkv+kvp pack. MODE 2: LN(R + gemm) (CB=1).
// DIVA 1: A-staging divides by (dden[row] + 1e-8)  (A = num, K = 96).
template<int NT, int KS, int MODE, int ACT, int DIVA = 0>
__global__ __launch_bounds__(256) void k_gemm2(const float* __restrict__ A, int K, int NcTot, int Nc16Tot,
    const u16* __restrict__ pkW, const float* __restrict__ bias, float* __restrict__ C,
    float* __restrict__ C2, const float* __restrict__ R, const float* __restrict__ sc,
    const float* __restrict__ bi, const float* __restrict__ dden)
{
  constexpr int Kpad = KS * 32;
  constexpr int SR = (Kpad*2 + 127) / 128 * 128;
  __shared__ __align__(16) char smem[32*SR + 256];
  const int tid = threadIdx.x;
  const int row0 = blockIdx.x * 32;
  for (int j = tid; j < 32*(Kpad/2); j += 256){
    int r = j / (Kpad/2); int c = (j - r*(Kpad/2)) * 2;
    const float* ap = A + (size_t)(row0 + r)*K + c;
    float f0 = (c < K) ? ap[0] : 0.f;
    float f1 = (c + 1 < K) ? ap[1] : 0.f;
    if (DIVA){
      float dv = 1.f / (dden[row0 + r] + 1e-8f);
      f0 *= dv; f1 *= dv;
    }
    *(u32*)(smem + swzb(r*SR + c*2, r)) = (u32)f2bf(f0) | ((u32)f2bf(f1) << 16);
  }
  __syncthreads();
  const int lane = tid & 63, w = tid >> 6;
  const int wr = w >> 1, wc = w & 1;
  const int r15 = lane & 15;
  const int kb = (lane >> 4) * 16;
  f32x4 acc[NT] = {};
  #pragma unroll
  for (int ks = 0; ks < KS; ks++){
    int row = wr*16 + r15;
    bf16x8 a = *(const bf16x8*)(smem + swzb(row*SR + ks*64 + kb, row));
    #pragma unroll
    for (int ct = 0; ct < NT; ct++){
      int t16g = blockIdx.y*(2*NT) + wc*NT + ct;
      bf16x8 b = *(const bf16x8*)(pkW + (((size_t)ks*Nc16Tot + t16g)*64 + lane)*8);
      acc[ct] = __builtin_amdgcn_mfma_f32_16x16x32_bf16(a, b, acc[ct], 0, 0, 0);
    }
  }
  const int colbase = blockIdx.y*(NT*32) + wc*(NT*16);
  if (MODE != 2){
    #pragma unroll
    for (int ct = 0; ct < NT; ct++){
      int col = colbase + ct*16 + r15;
      float bs = bias ? bias[col] : 0.f;
      #pragma unroll
      for (int q = 0; q < 4; q++){
        int row = row0 + wr*16 + (lane >> 4)*4 + q;
        float v = acc[ct][q] + bs;
        if (ACT == 1) v = lrelu(v);
        if (ACT == 2) v = v > 0.f ? v : 0.f;
        if (MODE == 0){
          C[(size_t)row*NcTot + col] = v;
        } else {
          if (col < 96){
            C[(size_t)row*288 + col] = v;
          } else if (col < 192){
            int hh = (col - 96) >> 3, cc = (col - 96) & 7;
            C2[(((size_t)hh*2048 + row) << 4) + cc] = v;
          } else {
            int hh = (col - 192) >> 3, cc = (col - 192) & 7;
            C2[(((size_t)hh*2048 + row) << 4) + 8 + cc] = v;
          }
        }
      }
    }
  } else {
    // fused residual + LayerNorm over 96 cols (CB=1)
    float* lnb = (float*)(smem + 32*SR);
    float vv[NT][4];
    float ps[4] = {0,0,0,0}, pq[4] = {0,0,0,0};
    #pragma unroll
    for (int ct = 0; ct < NT; ct++){
      int col = colbase + ct*16 + r15;
      float bs = bias[col];
      #pragma unroll
      for (int q = 0; q < 4; q++){
        int row = row0 + wr*16 + (lane >> 4)*4 + q;
        float v = acc[ct][q] + bs + R[(size_t)row*96 + col];
        vv[ct][q] = v;
        ps[q] += v;
        pq[q] += v*v;
      }
    }
    #pragma unroll
    for (int m = 1; m < 16; m <<= 1){
      #pragma unroll
      for (int q = 0; q < 4; q++){
        ps[q] += __shfl_xor(ps[q], m);
        pq[q] += __shfl_xor(pq[q], m);
      }
    }
    if (r15 == 0){
      #pragma unroll
      for (int q = 0; q < 4; q++){
        int row16 = (lane >> 4)*4 + q;
        lnb[(((wr*2 + wc)*16) + row16)*2]     = ps[q];
        lnb[(((wr*2 + wc)*16) + row16)*2 + 1] = pq[q];
      }
    }
    __syncthreads();
    #pragma unroll
    for (int ct = 0; ct < NT; ct++){
      int col = colbase + ct*16 + r15;
      float scv = sc[col], biv = bi[col];
      #pragma unroll
      for (int q = 0; q < 4; q++){
        int row16 = (lane >> 4)*4 + q;
        float s  = lnb[((wr*2)*16 + row16)*2]     + lnb[((wr*2+1)*16 + row16)*2];
        float ss = lnb[((wr*2)*16 + row16)*2 + 1] + lnb[((wr*2+1)*16 + row16)*2 + 1];
        float mean = s * (1.f/96.f);
        float var  = ss * (1.f/96.f) - mean*mean;
        float rs = rsqrtf(var + 1e-5f);
        int row = row0 + wr*16 + row16;
        C[(size_t)row*96 + col] = (vv[ct][q] - mean)*rs*scv + biv;
      }
    }
  }
}

// ---------------- attention v5: (head, 16-row) blocks, LDS-staged keys, shuffle+LDS combine ----------
__global__ __launch_bounds__(256) void k_attn5(const float* __restrict__ qkv, const float* __restrict__ kvp,
                                               float* __restrict__ obuf){
  __shared__ float kbuf[2][4096];
  __shared__ float part[4][16][12];
  const int tid = threadIdx.x;
  const int lane = tid & 63, w = tid >> 6;
  const int r = lane & 15, q = lane >> 4;
  const int head = blockIdx.x >> 7, rb = blockIdx.x & 127;
  const int row = rb*16 + r;
  const float* qp = qkv + (size_t)row*288 + head*8;
  float4 qa = *(const float4*)qp;
  float4 qb = *(const float4*)(qp + 4);
  const float* base = kvp + (size_t)head*32768;
  float4 st0 = *(const float4*)(base + tid*4);
  float4 st1 = *(const float4*)(base + 1024 + tid*4);
  float4 st2 = *(const float4*)(base + 2048 + tid*4);
  float4 st3 = *(const float4*)(base + 3072 + tid*4);
  *(float4*)&kbuf[0][tid*4]        = st0;
  *(float4*)&kbuf[0][1024 + tid*4] = st1;
  *(float4*)&kbuf[0][2048 + tid*4] = st2;
  *(float4*)&kbuf[0][3072 + tid*4] = st3;
  __syncthreads();
  float sm = 0.f;
  float o0=0,o1=0,o2=0,o3=0,o4=0,o5=0,o6=0,o7=0;
  for (int c = 0; c < 8; c++){
    if (c < 7){
      const float* nb = base + (c+1)*4096;
      st0 = *(const float4*)(nb + tid*4);
      st1 = *(const float4*)(nb + 1024 + tid*4);
      st2 = *(const float4*)(nb + 2048 + tid*4);
      st3 = *(const float4*)(nb + 3072 + tid*4);
    }
    const float* kp0 = &kbuf[c & 1][(w*64 + q)*16];
    #pragma unroll
    for (int i = 0; i < 16; i++){
      const float* kp = kp0 + i*64;
      float4 ka = *(const float4*)kp;
      float4 kb4 = *(const float4*)(kp + 4);
      float4 va = *(const float4*)(kp + 8);
      float4 vb = *(const float4*)(kp + 12);
      float s = qa.x*ka.x + qa.y*ka.y + qa.z*ka.z + qa.w*ka.w
              + qb.x*kb4.x + qb.y*kb4.y + qb.z*kb4.z + qb.w*kb4.w;
      s = fminf(s * 0.35355339059327373f, 60.f);
      float p = __expf(s);
      sm += p;
      o0 += p*va.x; o1 += p*va.y; o2 += p*va.z; o3 += p*va.w;
      o4 += p*vb.x; o5 += p*vb.y; o6 += p*vb.z; o7 += p*vb.w;
    }
    if (c < 7){
      float* wb = kbuf[(c+1) & 1];
      *(float4*)&wb[tid*4]        = st0;
      *(float4*)&wb[1024 + tid*4] = st1;
      *(float4*)&wb[2048 + tid*4] = st2;
      *(float4*)&wb[3072 + tid*4] = st3;
      __syncthreads();
    }
  }
  #pragma unroll
  for (int stx = 16; stx < 64; stx <<= 1){
    o0 += __shfl_xor(o0, stx); o1 += __shfl_xor(o1, stx);
    o2 += __shfl_xor(o2, stx); o3 += __shfl_xor(o3, stx);
    o4 += __shfl_xor(o4, stx); o5 += __shfl_xor(o5, stx);
    o6 += __shfl_xor(o6, stx); o7 += __shfl_xor(o7, stx);
    sm += __shfl_xor(sm, stx);
  }
  if (q == 0){
    float* pp = part[w][r];
    pp[0]=o0; pp[1]=o1; pp[2]=o2; pp[3]=o3; pp[4]=o4; pp[5]=o5; pp[6]=o6; pp[7]=o7; pp[8]=sm;
  }
  __syncthreads();
  if (tid < 128){
    int rr = tid >> 3, d = tid & 7;
    float o  = part[0][rr][d] + part[1][rr][d] + part[2][rr][d] + part[3][rr][d];
    float ss = part[0][rr][8] + part[1][rr][8] + part[2][rr][8] + part[3][rr][8];
    obuf[(size_t)(rb*16 + rr)*96 + head*8 + d] = o / ss;
  }
}

// ---------------- fused edge MLPs (packed weights from L2) ----------------
__global__ __launch_bounds__(256) void k_edge(const float* __restrict__ efr, const float* __restrict__ es,
    const u16* __restrict__ pk,
    const float* __restrict__ eb1, const float* __restrict__ eb2,
    const float* __restrict__ adb1, const float* __restrict__ adw2, const float* __restrict__ adb2,
    const float* __restrict__ arb1, const float* __restrict__ arw2, const float* __restrict__ arb2,
    u16* __restrict__ efnn, float* __restrict__ alpha)
{
  __shared__ __align__(16) char smem[16384];
  const int tid = threadIdx.x;
  const int e0 = blockIdx.x * 64;
  for (int j = tid; j < 64*16; j += 256){
    int r = j >> 4; int c = (j & 15) * 2;
    float f0 = 0.f, f1 = 0.f;
    if (c < 12)     f0 = (efr[(size_t)(e0+r)*12 + c]     + 1e-4f) / es[c];
    if (c + 1 < 12) f1 = (efr[(size_t)(e0+r)*12 + c + 1] + 1e-4f) / es[c+1];
    *(u32*)(smem + swzb(r*128 + c*2, r)) = (u32)f2bf(f0) | ((u32)f2bf(f1) << 16);
  }
  __syncthreads();
  const int lane = tid & 63, w = tid >> 6;
  const int r15 = lane & 15;

  auto store_lds = [&](f32x4* acc, int base, const float* bias){
    #pragma unroll
    for (int ct = 0; ct < 4; ct++){
      int col = ct*16 + r15;
      float bs = bias[col];
      #pragma unroll
      for (int q = 0; q < 4; q++){
        int row = w*16 + (lane >> 4)*4 + q;
        *(u16*)(smem + base + swzb(row*128 + col*2, row)) = f2bf(lrelu(acc[ct][q] + bs));
      }
    }
  };

  { f32x4 acc[4] = {};
    tile_gemm_gp<4,1,128,4>(smem, w*2048, pk + PK_EIN1, lane, acc);
    store_lds(acc, 8192, eb1); }
  __syncthreads();
  { f32x4 acc[4] = {};
    tile_gemm_gp<4,2,128,4>(smem, 8192 + w*2048, pk + PK_EIN2, lane, acc);
    store_lds(acc, 0, eb2); }
  __syncthreads();
  for (int j = tid; j < 2048; j += 256){
    int r = j >> 5;
    ((u32*)efnn)[e0*32 + j] = *(const u32*)(smem + swzb(r*128 + (j&31)*4, r));
  }
  { f32x4 acc[4] = {};
    tile_gemm_gp<4,2,128,4>(smem, w*2048, pk + PK_AD1, lane, acc);
    store_lds(acc, 8192, adb1); }
  __syncthreads();
  { int row = tid >> 2, part = tid & 3;
    float s = 0.f;
    #pragma unroll
    for (int i = 0; i < 16; i++){
      int k = part*16 + i;
      s += bf2f(*(const u16*)(smem + 8192 + swzb(row*128 + k*2, row))) * adw2[k];
    }
    s += __shfl_xor(s, 1); s += __shfl_xor(s, 2);
    if (part == 0) alpha[e0 + row] = 1.f / (1.f + __expf(-(s + adb2[0]))); }
  __syncthreads();
  { f32x4 acc[4] = {};
    tile_gemm_gp<4,2,128,4>(smem, w*2048, pk + PK_AR1, lane, acc);
    store_lds(acc, 8192, arb1); }
  __syncthreads();
  { int row = tid >> 2, part = tid & 3;
    float s = 0.f;
    #pragma unroll
    for (int i = 0; i < 16; i++){
      int k = part*16 + i;
      s += bf2f(*(const u16*)(smem + 8192 + swzb(row*128 + k*2, row))) * arw2[k];
    }
    s += __shfl_xor(s, 1); s += __shfl_xor(s, 2);
    if (part == 0) alpha[EE + e0 + row] = 1.f / (1.f + __expf(-(s + arb2[0]))); }
}

// ---------------- graph-conv v8: gc5x body, 2 blocks/node (chunks strided), atomic num --------
// P[N][384] = [P1|P2] with GC_B1 folded into p1c at init. (Measured optimum: 2-way split;
// 1-way=70, 4-way=90, dbuf=85, reg-A=121 — R10..R17 ladder.)
__global__ __launch_bounds__(256) void k_gc8(const float* __restrict__ P,
    const int2* __restrict__ sidx, const float* __restrict__ alphaS, const int* __restrict__ offs,
    const u16* __restrict__ wt2p, const float* __restrict__ b1, const float* __restrict__ b2,
    float* __restrict__ num)
{
  __shared__ __align__(16) char smem[26624];
  float* p1c  = (float*)(smem + 24576);
  int*   i2b  = (int*)  (smem + 25344);
  float* alph = (float*)(smem + 25600);
  float* part = (float*)(smem + 25856);
  const int tid = threadIdx.x;
  const int lane = tid & 63, w = tid >> 6;
  const int wr = w >> 1, wc = w & 1;
  const int r15 = lane & 15;
  const int kb = (lane >> 4) * 16;
  const int n = blockIdx.x >> 1, sp = blockIdx.x & 1;
  const int rbeg = offs[n], rend = offs[n + 1];
  if (tid < 192) p1c[tid] = P[(size_t)n*384 + tid] + b1[tid];
  float b2r[3];
  #pragma unroll
  for (int ct = 0; ct < 3; ct++) b2r[ct] = b2[wc*48 + ct*16 + r15];
  float cs0 = 0.f, cs1 = 0.f, cs2 = 0.f;

  const int total = rend - rbeg + (n == 0 ? 1 : 0);   // node 0: +1 virtual row
  const int nch = (total + 63) >> 6;

  int pm_i2 = 0; float pm_al = 0.f;
  auto fetch_meta = [&](int c){
    if (tid < 64){
      int pos = rbeg + c*64 + tid;
      if (pos < rend){
        pm_i2 = sidx[pos].y;
        pm_al = alphaS[pos];
      } else if (n == 0 && pos == rend){ pm_i2 = 0; pm_al = 2048.f; }
      else { pm_i2 = 0; pm_al = 0.f; }
    }
  };
  fetch_meta(sp);
  __syncthreads();   // p1c visible
  for (int c = sp; c < nch; c += 2){
    if (tid < 64){ i2b[tid] = pm_i2; alph[tid] = pm_al; }
    __syncthreads();
    for (int j = tid; j < 1536; j += 256){
      int r = j / 24, q = j - (j/24)*24;
      int c8 = q * 8;
      const float* p2 = P + (size_t)i2b[r]*384 + 192 + c8;
      float4 b0 = *(const float4*)p2, b1v = *(const float4*)(p2 + 4);
      const float* pc = p1c + c8;
      u16 pkv[8];
      pkv[0]=f2bf(lrelu(pc[0]+b0.x)); pkv[1]=f2bf(lrelu(pc[1]+b0.y));
      pkv[2]=f2bf(lrelu(pc[2]+b0.z)); pkv[3]=f2bf(lrelu(pc[3]+b0.w));
      pkv[4]=f2bf(lrelu(pc[4]+b1v.x)); pkv[5]=f2bf(lrelu(pc[5]+b1v.y));
      pkv[6]=f2bf(lrelu(pc[6]+b1v.z)); pkv[7]=f2bf(lrelu(pc[7]+b1v.w));
      *(bf16x8*)(smem + swzb(r*384 + c8*2, r)) = *(bf16x8*)pkv;
    }
    __syncthreads();
    float ar[2][4];
    #pragma unroll
    for (int rt = 0; rt < 2; rt++)
      #pragma unroll
      for (int q = 0; q < 4; q++)
        ar[rt][q] = alph[wr*32 + rt*16 + (lane >> 4)*4 + q];
    if (c + 2 < nch) fetch_meta(c + 2);        // overlaps MFMA below
    f32x4 acc2[2][3] = {};
    #pragma unroll
    for (int ks = 0; ks < 6; ks++){
      bf16x8 a[2];
      #pragma unroll
      for (int rt = 0; rt < 2; rt++){
        int row = wr*32 + rt*16 + r15;
        a[rt] = *(const bf16x8*)(smem + swzb(row*384 + ks*64 + kb, row));
      }
      #pragma unroll
      for (int ct = 0; ct < 3; ct++){
        bf16x8 b = *(const bf16x8*)(wt2p + (((size_t)ks*6 + wc*3 + ct)*64 + lane)*8);
        #pragma unroll
        for (int rt = 0; rt < 2; rt++)
          acc2[rt][ct] = __builtin_amdgcn_mfma_f32_16x16x32_bf16(a[rt], b, acc2[rt][ct], 0, 0, 0);
      }
    }
    #pragma unroll
    for (int rt = 0; rt < 2; rt++){
      #pragma unroll
      for (int q = 0; q < 4; q++){
        float aw = ar[rt][q];
        cs0 += aw * lrelu(acc2[rt][0][q] + b2r[0]);
        cs1 += aw * lrelu(acc2[rt][1][q] + b2r[1]);
        cs2 += aw * lrelu(acc2[rt][2][q] + b2r[2]);
      }
    }
    __syncthreads();
  }
  #pragma unroll
  for (int stx = 16; stx < 64; stx <<= 1){
    cs0 += __shfl_xor(cs0, stx);
    cs1 += __shfl_xor(cs1, stx);
    cs2 += __shfl_xor(cs2, stx);
  }
  if (lane < 16){
    part[(w*3 + 0)*16 + lane] = cs0;
    part[(w*3 + 1)*16 + lane] = cs1;
    part[(w*3 + 2)*16 + lane] = cs2;
  }
  __syncthreads();
  if (tid < 96){
    int wc2 = tid / 48, rem = tid - wc2*48;
    int ct = rem / 16, rr = rem - ct*16;
    float tot = part[(wc2*3 + ct)*16 + rr] + part[((2 + wc2)*3 + ct)*16 + rr];
    atomicAdd(num + (size_t)n*96 + tid, tot);
  }
}

// ---------------- final predictor v3: hp[N][192] combined, EN_B1 here ----------------
__global__ __launch_bounds__(256) void k_final3(const float* __restrict__ hp,
    const int* __restrict__ ei, const u16* __restrict__ efnn, const float* __restrict__ efr,
    const float* __restrict__ es, const u16* __restrict__ encp, const float* __restrict__ enb1,
    const float* __restrict__ enw2, const float* __restrict__ enb2, float* __restrict__ out)
{
  __shared__ __align__(16) char smem[38400];
  float* etb = (float*)(smem + 12288);
  float* w2s = (float*)(smem + 37120);
  float* b1s = (float*)(smem + 37504);
  int*   eix = (int*)  (smem + 37888);
  const int tid = threadIdx.x;
  const int e0 = blockIdx.x * 64;
  for (int j = tid; j < 768; j += 256){
    int r = j / 12, q = j - (j/12)*12;
    int e = e0 + r;
    bf16x8 v;
    if (q < 8){
      v = *(const bf16x8*)(efnn + (size_t)e*64 + q*8);
    } else if (q < 10){
      u16 pkv[8];
      #pragma unroll
      for (int i = 0; i < 8; i++){
        int cc = (q - 8)*8 + i;
        pkv[i] = (cc < 12) ? f2bf((efr[(size_t)e*12 + cc] + 1e-4f) / es[cc]) : (u16)0;
      }
      v = *(bf16x8*)pkv;
    } else {
      v = bf16x8{0,0,0,0,0,0,0,0};
    }
    *(bf16x8*)(smem + swzb(r*192 + q*16, r)) = v;
  }
  if (tid < 96) w2s[tid] = enw2[tid];
  else if (tid < 192) b1s[tid - 96] = enb1[tid - 96];
  if (tid < 64){ eix[2*tid] = ei[2*(e0+tid)]; eix[2*tid+1] = ei[2*(e0+tid)+1]; }
  __syncthreads();
  const int lane = tid & 63, w = tid >> 6;
  const int r15 = lane & 15;
  f32x4 acc[6] = {};
  tile_gemm_gp<6,3,192,6>(smem, w*16*192, encp, lane, acc);
  #pragma unroll
  for (int ct = 0; ct < 6; ct++){
    int col = ct*16 + r15;
    #pragma unroll
    for (int q = 0; q < 4; q++){
      int row = w*16 + (lane >> 4)*4 + q;
      etb[row*97 + col] = acc[ct][q];
    }
  }
  __syncthreads();
  int r = tid >> 2, part = tid & 3;
  int s1 = eix[2*r], s2 = eix[2*r + 1];
  const float* p1 = hp + (size_t)s1*192 + part*24;
  const float* p2 = hp + (size_t)s2*192 + 96 + part*24;
  const float* et = etb + r*97 + part*24;
  const float* wz = w2s + part*24;
  const float* bz = b1s + part*24;
  float s = 0.f;
  #pragma unroll
  for (int i = 0; i < 24; i++){
    float v = et[i] + p1[i] + p2[i] + bz[i];
    s += lrelu(v) * wz[i];
  }
  s += __shfl_xor(s, 1); s += __shfl_xor(s, 2);
  if (part == 0) out[e0 + r] = 1.f / (1.f + __expf(-(s + enb2[0])));
}

// ---------------- host ----------------
extern "C" void kernel_launch(void* const* d_in, const int* in_sizes, int n_in,
                              void* d_out, int out_size, void* d_ws, size_t ws_size,
                              hipStream_t stream) {
  (void)in_sizes; (void)n_in; (void)out_size; (void)ws_size;
  const float* X      = (const float*)d_in[0];
  const float* EFR    = (const float*)d_in[1];
  const int*   EI     = (const int*)  d_in[2];
  const float* NS     = (const float*)d_in[3];
  const float* ES     = (const float*)d_in[4];
  const float* IN_W1  = (const float*)d_in[5];
  const float* IN_B1  = (const float*)d_in[6];
  const float* IN_W2  = (const float*)d_in[7];
  const float* IN_B2  = (const float*)d_in[8];
  const float* QKV_W  = (const float*)d_in[9];
  const float* QKV_B  = (const float*)d_in[10];
  const float* OUT_W  = (const float*)d_in[11];
  const float* OUT_B  = (const float*)d_in[12];
  const float* LN1S   = (const float*)d_in[13];
  const float* LN1B   = (const float*)d_in[14];
  const float* FFW1   = (const float*)d_in[15];
  const float* FFB1   = (const float*)d_in[16];
  const float* FFW2   = (const float*)d_in[17];
  const float* FFB2   = (const float*)d_in[18];
  const float* LN2S   = (const float*)d_in[19];
  const float* LN2B   = (const float*)d_in[20];
  const float* EIN_W1 = (const float*)d_in[21];
  const float* EIN_B1 = (const float*)d_in[22];
  const float* EIN_W2 = (const float*)d_in[23];
  const float* EIN_B2 = (const float*)d_in[24];
  const float* AD_W1  = (const float*)d_in[25];
  const float* AD_B1  = (const float*)d_in[26];
  const float* AD_W2  = (const float*)d_in[27];
  const float* AD_B2  = (const float*)d_in[28];
  const float* AR_W1  = (const float*)d_in[29];
  const float* AR_B1  = (const float*)d_in[30];
  const float* AR_W2  = (const float*)d_in[31];
  const float* AR_B2  = (const float*)d_in[32];
  const float* GC_W1  = (const float*)d_in[33];
  const float* GC_B1  = (const float*)d_in[34];
  const float* GC_W2  = (const float*)d_in[35];
  const float* GC_B2  = (const float*)d_in[36];
  const float* EN_W1  = (const float*)d_in[37];
  const float* EN_B1  = (const float*)d_in[38];
  const float* EN_W2  = (const float*)d_in[39];
  const float* EN_B2  = (const float*)d_in[40];

  char* ws = (char*)d_ws;
  u16*   pool   = (u16*)  (ws + WS_WT);
  u16*   efnn   = (u16*)  (ws + WS_EFNN);
  float* alpha  = (float*)(ws + WS_ALPHA);
  float* h      = (float*)(ws + WS_H);
  float* qkvb   = (float*)(ws + WS_QKV);
  float* obuf   = (float*)(ws + WS_OBUF);
  float* tmpA   = (float*)(ws + WS_TMPA);
  float* tmpB   = (float*)(ws + WS_TMPB);
  float* x1     = (float*)(ws + WS_X1);
  float* num    = (float*)(ws + WS_NUM);
  float* den    = (float*)(ws + WS_DEN);
  float* xs     = (float*)(ws + WS_XS);
  int2*  sidx   = (int2*) (ws + WS_SIDX);
  float* alphaS = (float*)(ws + WS_ALPS);
  int*   cnt    = (int*)  (ws + WS_CNT);
  int*   offs   = (int*)  (ws + WS_OFFS);
  u16*   pk     = (u16*)  (ws + WS_PK);
  float* P      = (float*)(ws + WS_QKV);   // [N][384], spans QKV+OBUF (dead after encoder)
  float* hp     = (float*)(ws + WS_TMPB);  // [N][192]
  float* kvp    = (float*)(ws + WS_ALPHA); // reuse: alpha dead after k_scatter

  // ---- weight conversion jobs ----
  CvtJobs jb;
  int idx = 0, cum = 0;
  auto addjob = [&](const float* s, int K, int Nc, int Kp){
    jb.src[idx] = s; jb.K[idx] = K; jb.Nc[idx] = Nc; jb.Kp[idx] = Kp;
    jb.cum[idx] = cum; cum += Nc * Kp; idx++;
  };
  addjob(IN_W1, 19, 96, 32);
  addjob(IN_W2, 96, 96, 96);
  for (int l = 0; l < 3; l++) addjob(QKV_W + (size_t)l*96*288, 96, 288, 96);
  for (int l = 0; l < 3; l++) addjob(OUT_W + (size_t)l*96*96,  96, 96,  96);
  for (int l = 0; l < 3; l++) addjob(FFW1  + (size_t)l*96*192, 96, 192, 96);
  for (int l = 0; l < 3; l++) addjob(FFW2  + (size_t)l*192*96, 192, 96, 192);
  addjob(EIN_W1, 12, 64, 32);
  addjob(EIN_W2, 64, 64, 64);
  addjob(AD_W1,  64, 64, 64);
  addjob(AR_W1,  64, 64, 64);
  for (int i = 0; i < 2; i++){
    addjob(GC_W1 + (size_t)i*192*192,          96, 192, 96);
    addjob(GC_W1 + (size_t)i*192*192 + 96*192, 96, 192, 96);
  }
  for (int i = 0; i < 2; i++) addjob(GC_W2 + (size_t)i*192*96, 192, 96, 192);
  addjob(EN_W1,            96, 96, 96);
  addjob(EN_W1 + 96*96,    96, 96, 96);
  addjob(EN_W1 + 192*96,   76, 96, 96);
  jb.cum[idx] = cum;

  k_cvt<<<(POOL_TOT + 255)/256, 256, 0, stream>>>(jb, pool);

  // ---- fragment packing jobs; ORDER MUST MATCH PK_* offsets ----
  PkJobs pj;
  int pidx = 0, pcum = 0;
  auto addpk = [&](int srcOff, int Nc16, int Ks, int Kp){
    pj.srcOff[pidx] = srcOff; pj.Nc16[pidx] = Nc16; pj.Kp[pidx] = Kp;
    pj.cum[pidx] = pcum; pcum += Nc16 * Ks * 512; pidx++;
  };
  addpk(EIN1T, 4, 1, 32);
  addpk(EIN2T, 4, 2, 64);
  addpk(AD1T,  4, 2, 64);
  addpk(AR1T,  4, 2, 64);
  addpk(GC2T,          6, 6, 192);
  addpk(GC2T + 18432,  6, 6, 192);
  addpk(ENCT, 6, 3, 96);
  for (int l = 0; l < 3; l++) addpk(QKVT + l*27648, 18, 3, 96);
  for (int l = 0; l < 3; l++) addpk(OUTT + l*9216,   6, 3, 96);
  for (int l = 0; l < 3; l++) addpk(FF1T + l*18432, 12, 3, 96);
  for (int l = 0; l < 3; l++) addpk(FF2T + l*18432,  6, 6, 192);
  addpk(IN1T, 6, 1, 32);
  addpk(IN2T, 6, 3, 96);
  for (int i = 0; i < 2; i++) addpk(GC1T + i*36864, 24, 3, 96);   // A|B combined
  addpk(ENAT, 12, 3, 96);                                        // ENA|ENB combined
  for (int z = pidx; z <= 27; z++) pj.cum[z] = pcum;              // == PK_TOT

  k_pack<<<(PK_TOT + 255)/256, 256, 0, stream>>>(pj, pool, pk);

  // ---- node embedding ----
  k_xscale<<<(NN*19 + 255)/256, 256, 0, stream>>>(X, NS, xs);
  k_gemm2<3,1,0,1><<<dim3(64,1), 256, 0, stream>>>(xs, 19, 96, 6, pk + PK_IN1, IN_B1, tmpA,
                                                   nullptr, nullptr, nullptr, nullptr, nullptr);
  k_gemm2<3,3,0,1><<<dim3(64,1), 256, 0, stream>>>(tmpA, 96, 96, 6, pk + PK_IN2, IN_B2, h,
                                                   nullptr, nullptr, nullptr, nullptr, nullptr);

  // ---- edge MLPs + attention weights ----
  k_edge<<<EE/64, 256, 0, stream>>>(EFR, ES, pk, EIN_B1, EIN_B2,
                                    AD_B1, AD_W2, AD_B2, AR_B1, AR_W2, AR_B2, efnn, alpha);

  // ---- destination sort + den ----
  (void)hipMemsetAsync(cnt, 0, NN*4, stream);
  k_hist<<<(2*EE)/256, 256, 0, stream>>>(EI, cnt);
  k_scan<<<1, 256, 0, stream>>>(cnt, offs);
  (void)hipMemsetAsync(cnt, 0, NN*4, stream);
  k_scatter<<<(2*EE)/256, 256, 0, stream>>>(EI, alpha, offs, cnt, sidx, alphaS);
  k_dens<<<NN/4, 256, 0, stream>>>(offs, alphaS, den);

  // ---- 3 encoder layers (5 launches each) ----
  for (int l = 0; l < 3; l++){
    k_gemm2<3,3,1,0><<<dim3(64,3), 256, 0, stream>>>(h, 96, 288, 18, pk + PK_QKV + l*27648,
                                                     QKV_B + l*288, qkvb, kvp, nullptr, nullptr, nullptr, nullptr);
    k_attn5<<<1536, 256, 0, stream>>>(qkvb, kvp, obuf);
    k_gemm2<3,3,2,0><<<dim3(64,1), 256, 0, stream>>>(obuf, 96, 96, 6, pk + PK_OUT + l*9216,
                                                     OUT_B + l*96, x1, nullptr, h, LN1S + l*96, LN1B + l*96, nullptr);
    k_gemm2<3,3,0,2><<<dim3(64,2), 256, 0, stream>>>(x1, 96, 192, 12, pk + PK_FF1 + l*18432,
                                                     FFB1 + l*192, tmpB, nullptr, nullptr, nullptr, nullptr, nullptr);
    k_gemm2<3,6,2,0><<<dim3(64,1), 256, 0, stream>>>(tmpB, 192, 96, 6, pk + PK_FF2 + l*18432,
                                                     FFB2 + l*96, h, nullptr, x1, LN2S + l*96, LN2B + l*96, nullptr);
  }

  // ---- 2 graph-conv iterations: P = [h@W1a | h@W1b] (one gemm), 2-way split gc, atomic num ----
  for (int it = 0; it < 2; it++){
    if (it == 0){
      k_gemm2<3,3,0,0><<<dim3(64,3), 256, 0, stream>>>(h, 96, 384, 24, pk + PK_GC1 + it*36864,
                                                       nullptr, P, nullptr, nullptr, nullptr, nullptr, nullptr);
    } else {
      k_gemm2<3,3,0,0,1><<<dim3(64,3), 256, 0, stream>>>(num, 96, 384, 24, pk + PK_GC1 + it*36864,
                                                         nullptr, P, nullptr, nullptr, nullptr, nullptr, den);
    }
    (void)hipMemsetAsync(num, 0, NN*96*4, stream);
    k_gc8<<<2*NN, 256, 0, stream>>>(P, sidx, alphaS, offs,
                                    pk + PK_GC2 + it*18432, GC_B1 + it*192, GC_B2 + it*96, num);
  }

  // ---- final predictor: hp = [num/den @ ENA | @ ENB] (one gemm, no bias) ----
  k_gemm2<3,3,0,0,1><<<dim3(64,2), 256, 0, stream>>>(num, 96, 192, 12, pk + PK_ENAB,
                                                     nullptr, hp, nullptr, nullptr, nullptr, nullptr, den);
  k_final3<<<EE/64, 256, 0, stream>>>(hp, EI, efnn, EFR, ES,
                                      pk + PK_ENC, EN_B1, EN_W2, EN_B2, (float*)d_out);
}

// Round 19
// 588.490 us; speedup vs baseline: 1.0663x; 1.0017x over previous
//
#include <hip/hip_runtime.h>

// ---------------- constants ----------------
#define NN 2048
#define EE 262144

typedef __attribute__((ext_vector_type(8))) short bf16x8;
typedef __attribute__((ext_vector_type(4))) float f32x4;
typedef unsigned int u32;
typedef unsigned short u16;

__device__ __forceinline__ u16 f2bf(float f){
  u32 u = __builtin_bit_cast(u32, f);
  u32 r = u + 0x7FFFu + ((u >> 16) & 1u);
  return (u16)(r >> 16);
}
__device__ __forceinline__ float bf2f(u16 h){
  u32 u = ((u32)h) << 16;
  return __builtin_bit_cast(float, u);
}
__device__ __forceinline__ int swzb(int byte, int row){ return byte ^ ((row & 7) << 4); }
__device__ __forceinline__ float lrelu(float v){ return fmaxf(v, 0.01f * v); }

// ---------------- ws layout (bytes) ----------------
static const size_t WS_WT    = 0;                    // u16 pool (772096 B)
static const size_t WS_EFNN  = 772096;               // u16 E*64
static const size_t WS_ALPHA = WS_EFNN  + 33554432;  // f32 2E ; kvp reuses this after sort
static const size_t WS_H     = WS_ALPHA + 2097152;   // f32 N*96
static const size_t WS_QKV   = WS_H     + 786432;    // f32 N*288 ; P[N][384] spans QKV+OBUF
static const size_t WS_OBUF  = WS_QKV   + 2359296;   // f32 N*96
static const size_t WS_TMPA  = WS_OBUF  + 786432;    // f32 N*96
static const size_t WS_TMPB  = WS_TMPA  + 786432;    // f32 N*192 ; hp[N][192] reuses this
static const size_t WS_X1    = WS_TMPB  + 1572864;   // f32 N*96
static const size_t WS_NUM   = WS_X1    + 786432;    // f32 N*96
static const size_t WS_DEN   = WS_NUM   + 786432;    // f32 N (pad)
static const size_t WS_XS    = WS_DEN   + 8192;      // f32 N*19 (pad)
static const size_t WS_HBF   = WS_XS    + 155648;    // (dead)
static const size_t WS_META  = WS_HBF   + 393216;    // int2 2E  (i2, alpha-bits) sorted
static const size_t WS_ALPS  = WS_META  + 4194304;   // (dead)
static const size_t WS_CNT   = WS_ALPS  + 2097152;   // int N
static const size_t WS_OFFS  = WS_CNT   + 8192;      // int N+1 (pad)
static const size_t WS_PK    = WS_OFFS  + 8192;      // u16 fragment-packed weights (772096 B)

// pool element offsets (bf16, weights transposed [Nc][Kpad])
#define IN1T 0
#define IN2T 3072
#define QKVT 12288
#define OUTT 95232
#define FF1T 122880
#define FF2T 178176
#define EIN1T 233472
#define EIN2T 235520
#define AD1T 239616
#define AR1T 243712
#define GC1T 247808
#define GC2T 321536
#define ENAT 358400
#define ENBT 367616
#define ENCT 376832
#define POOL_TOT 386048

// packed-fragment offsets (u16 elements within pk)
#define PK_EIN1 0
#define PK_EIN2 2048
#define PK_AD1  6144
#define PK_AR1  10240
#define PK_GC2  14336   /* + it*18432 */
#define PK_ENC  51200
#define PK_QKV  60416   /* + l*27648 */
#define PK_OUT  143360  /* + l*9216 */
#define PK_FF1  171008  /* + l*18432 */
#define PK_FF2  226304  /* + l*18432 */
#define PK_IN1  281600
#define PK_IN2  284672
#define PK_GC1  293888  /* + it*36864 ; A|B combined, Nc16=24 */
#define PK_ENAB 367616  /* A|B combined, Nc16=12 */
#define PK_TOT  386048

// ---------------- weight convert (f32 -> bf16, transposed, K-padded) ----------------
struct CvtJobs {
  const float* src[27];
  int K[27], Nc[27], Kp[27];
  int cum[28];
};

__global__ __launch_bounds__(256) void k_cvt(CvtJobs jb, u16* __restrict__ pool){
  int i = blockIdx.x * 256 + threadIdx.x;
  if (i >= jb.cum[27]) return;
  int j = 0;
  while (i >= jb.cum[j + 1]) j++;
  int loc = i - jb.cum[j];
  int Kp = jb.Kp[j];
  int n = loc / Kp, k = loc - n * Kp;
  float v = (k < jb.K[j]) ? jb.src[j][(size_t)k * jb.Nc[j] + n] : 0.f;
  pool[i] = f2bf(v);
}

// repack [Nc][Kp] -> MFMA-fragment lane order: pk[cum + ((ks*Nc16+t16)*64+lane)*8+j]
struct PkJobs {
  int srcOff[27], Nc16[27], Kp[27];
  int cum[28];
};

__global__ __launch_bounds__(256) void k_pack(PkJobs jb, const u16* __restrict__ pool,
                                              u16* __restrict__ pk){
  int i = blockIdx.x * 256 + threadIdx.x;
  if (i >= jb.cum[27]) return;
  int j = 0;
  while (i >= jb.cum[j + 1]) j++;
  int loc = i - jb.cum[j];
  int jj = loc & 7, lane = (loc >> 3) & 63, tk = loc >> 9;
  int Nc16 = jb.Nc16[j];
  int ks = tk / Nc16, t16 = tk - ks * Nc16;
  pk[i] = pool[jb.srcOff[j] + (t16*16 + (lane & 15)) * jb.Kp[j] + ks*32 + (lane >> 4)*8 + jj];
}

__global__ __launch_bounds__(256) void k_xscale(const float* __restrict__ X, const float* __restrict__ ns,
                                                float* __restrict__ xs){
  int i = blockIdx.x * 256 + threadIdx.x;
  if (i < NN * 19) xs[i] = X[i] / ns[i % 19];
}

// ---------------- destination sort (counting sort over 2E edge rows) ----------------
__global__ __launch_bounds__(256) void k_hist(const int* __restrict__ ei, int* __restrict__ cnt){
  int g = blockIdx.x * 256 + threadIdx.x;
  int i1 = (g < EE) ? ei[2*g] : ei[2*(g - EE) + 1];
  atomicAdd(cnt + i1, 1);
}

__global__ __launch_bounds__(256) void k_scan(const int* __restrict__ cnt, int* __restrict__ offs){
  __shared__ int wsum[4], wbase[4];
  int t = threadIdx.x;
  int base = t * 8;
  int c[8]; int T = 0;
  #pragma unroll
  for (int i = 0; i < 8; i++){ c[i] = cnt[base + i]; T += c[i]; }
  int lane = t & 63, wv = t >> 6;
  int inc = T;
  #pragma unroll
  for (int st = 1; st < 64; st <<= 1){
    int v = __shfl_up(inc, st);
    if (lane >= st) inc += v;
  }
  if (lane == 63) wsum[wv] = inc;
  __syncthreads();
  if (t == 0){ int r = 0; for (int w2 = 0; w2 < 4; w2++){ wbase[w2] = r; r += wsum[w2]; } }
  __syncthreads();
  int run = wbase[wv] + inc - T;
  #pragma unroll
  for (int i = 0; i < 8; i++){ offs[base + i] = run; run += c[i]; }
  if (t == 255) offs[2048] = run;
}

// meta[pos] = (i2, alpha-bits): i1 is implied by the segment (gc8 block id), so the
// scattered payload is ONE 8B store/edge instead of 12B in two stores (R18 post-mortem:
// scattered-store line bounce gave 6x write amplification; fewer scattered bytes = less).
__global__ __launch_bounds__(256) void k_scatter(const int* __restrict__ ei, const float* __restrict__ alpha,
    const int* __restrict__ offs, int* __restrict__ rk, int2* __restrict__ meta){
  int g = blockIdx.x * 256 + threadIdx.x;
  int i1, i2;
  if (g < EE){ i1 = ei[2*g]; i2 = ei[2*g + 1]; }
  else { int gg = g - EE; i1 = ei[2*gg + 1]; i2 = ei[2*gg]; }
  float al = alpha[g];
  int r = atomicAdd(rk + i1, 1);
  int pos = offs[i1] + r;
  meta[pos] = make_int2(i2, __float_as_int(al));
}

__global__ __launch_bounds__(256) void k_dens(const int* __restrict__ offs, const int2* __restrict__ meta,
                                              float* __restrict__ den){
  int n = blockIdx.x * 4 + (threadIdx.x >> 6);
  int lane = threadIdx.x & 63;
  int b = offs[n], e = offs[n + 1];
  float s = 0.f;
  for (int i = b + lane; i < e; i += 64) s += __int_as_float(meta[i].y);
  #pragma unroll
  for (int st = 1; st < 64; st <<= 1) s += __shfl_xor(s, st);
  if (lane == 0) den[n] = s + (n == 0 ? 2048.f : 0.f);
}

// ---------------- MFMA tile helper (packed B from L2) ----------------
template<int NT, int KS, int SR, int NC16>
__device__ __forceinline__ void tile_gemm_gp(const char* sm, int aBase, const u16* __restrict__ Wp,
                                             int lane, f32x4* acc){
  const int r15 = lane & 15;
  const int kb = (lane >> 4) * 16;
  #pragma unroll
  for (int ks = 0; ks < KS; ks++){
    bf16x8 a = *(const bf16x8*)(sm + aBase + swzb(r15*SR + ks*64 + kb, r15));
    #pragma unroll
    for (int ct = 0; ct < NT; ct++){
      bf16x8 b = *(const bf16x8*)(Wp + (((size_t)ks*NC16 + ct)*64 + lane)*8);
      acc[ct] = __builtin_amdgcn_mfma_f32_16x16x32_bf16(a, b, acc[ct], 0, 0, 0);
    }
  }
}

// ---------------- gemm v2: 32-row x (2*NT*16)-col tiles, packed B, fused epilogues --------------
// grid (M/32, CB). MODE 0: plain. MODE 1: qkv+kvp pack. MODE 2: LN(R + gemm) (CB=1).
// DIVA 1: A-staging divides by (dden[row] + 1e-8)  (A = num, K = 96).
template<int NT, int KS, int MODE, int ACT, int DIVA = 0>
__global__ __launch_bounds__(256) void k_gemm2(const float* __restrict__ A, int K, int NcTot, int Nc16Tot,
    const u16* __restrict__ pkW, const float* __restrict__ bias, float* __restrict__ C,
    float* __restrict__ C2, const float* __restrict__ R, const float* __restrict__ sc,
    const float* __restrict__ bi, const float* __restrict__ dden)
{
  constexpr int Kpad = KS * 32;
  constexpr int SR = (Kpad*2 + 127) / 128 * 128;
  __shared__ __align__(16) char smem[32*SR + 256];
  const int tid = threadIdx.x;
  const int row0 = blockIdx.x * 32;
  for (int j = tid; j < 32*(Kpad/2); j += 256){
    int r = j / (Kpad/2); int c = (j - r*(Kpad/2)) * 2;
    const float* ap = A + (size_t)(row0 + r)*K + c;
    float f0 = (c < K) ? ap[0] : 0.f;
    float f1 = (c + 1 < K) ? ap[1] : 0.f;
    if (DIVA){
      float dv = 1.f / (dden[row0 + r] + 1e-8f);
      f0 *= dv; f1 *= dv;
    }
    *(u32*)(smem + swzb(r*SR + c*2, r)) = (u32)f2bf(f0) | ((u32)f2bf(f1) << 16);
  }
  __syncthreads();
  const int lane = tid & 63, w = tid >> 6;
  const int wr = w >> 1, wc = w & 1;
  const int r15 = lane & 15;
  const int kb = (lane >> 4) * 16;
  f32x4 acc[NT] = {};
  #pragma unroll
  for (int ks = 0; ks < KS; ks++){
    int row = wr*16 + r15;
    bf16x8 a = *(const bf16x8*)(smem + swzb(row*SR + ks*64 + kb, row));
    #pragma unroll
    for (int ct = 0; ct < NT; ct++){
      int t16g = blockIdx.y*(2*NT) + wc*NT + ct;
      bf16x8 b = *(const bf16x8*)(pkW + (((size_t)ks*Nc16Tot + t16g)*64 + lane)*8);
      acc[ct] = __builtin_amdgcn_mfma_f32_16x16x32_bf16(a, b, acc[ct], 0, 0, 0);
    }
  }
  const int colbase = blockIdx.y*(NT*32) + wc*(NT*16);
  if (MODE != 2){
    #pragma unroll
    for (int ct = 0; ct < NT; ct++){
      int col = colbase + ct*16 + r15;
      float bs = bias ? bias[col] : 0.f;
      #pragma unroll
      for (int q = 0; q < 4; q++){
        int row = row0 + wr*16 + (lane >> 4)*4 + q;
        float v = acc[ct][q] + bs;
        if (ACT == 1) v = lrelu(v);
        if (ACT == 2) v = v > 0.f ? v : 0.f;
        if (MODE == 0){
          C[(size_t)row*NcTot + col] = v;
        } else {
          if (col < 96){
            C[(size_t)row*288 + col] = v;
          } else if (col < 192){
            int hh = (col - 96) >> 3, cc = (col - 96) & 7;
            C2[(((size_t)hh*2048 + row) << 4) + cc] = v;
          } else {
            int hh = (col - 192) >> 3, cc = (col - 192) & 7;
            C2[(((size_t)hh*2048 + row) << 4) + 8 + cc] = v;
          }
        }
      }
    }
  } else {
    // fused residual + LayerNorm over 96 cols (CB=1)
    float* lnb = (float*)(smem + 32*SR);
    float vv[NT][4];
    float ps[4] = {0,0,0,0}, pq[4] = {0,0,0,0};
    #pragma unroll
    for (int ct = 0; ct < NT; ct++){
      int col = colbase + ct*16 + r15;
      float bs = bias[col];
      #pragma unroll
      for (int q = 0; q < 4; q++){
        int row = row0 + wr*16 + (lane >> 4)*4 + q;
        float v = acc[ct][q] + bs + R[(size_t)row*96 + col];
        vv[ct][q] = v;
        ps[q] += v;
        pq[q] += v*v;
      }
    }
    #pragma unroll
    for (int m = 1; m < 16; m <<= 1){
      #pragma unroll
      for (int q = 0; q < 4; q++){
        ps[q] += __shfl_xor(ps[q], m);
        pq[q] += __shfl_xor(pq[q], m);
      }
    }
    if (r15 == 0){
      #pragma unroll
      for (int q = 0; q < 4; q++){
        int row16 = (lane >> 4)*4 + q;
        lnb[(((wr*2 + wc)*16) + row16)*2]     = ps[q];
        lnb[(((wr*2 + wc)*16) + row16)*2 + 1] = pq[q];
      }
    }
    __syncthreads();
    #pragma unroll
    for (int ct = 0; ct < NT; ct++){
      int col = colbase + ct*16 + r15;
      float scv = sc[col], biv = bi[col];
      #pragma unroll
      for (int q = 0; q < 4; q++){
        int row16 = (lane >> 4)*4 + q;
        float s  = lnb[((wr*2)*16 + row16)*2]     + lnb[((wr*2+1)*16 + row16)*2];
        float ss = lnb[((wr*2)*16 + row16)*2 + 1] + lnb[((wr*2+1)*16 + row16)*2 + 1];
        float mean = s * (1.f/96.f);
        float var  = ss * (1.f/96.f) - mean*mean;
        float rs = rsqrtf(var + 1e-5f);
        int row = row0 + wr*16 + row16;
        C[(size_t)row*96 + col] = (vv[ct][q] - mean)*rs*scv + biv;
      }
    }
  }
}

// ---------------- attention v5: (head, 16-row) blocks, LDS-staged keys, shuffle+LDS combine ----------
__global__ __launch_bounds__(256) void k_attn5(const float* __restrict__ qkv, const float* __restrict__ kvp,
                                               float* __restrict__ obuf){
  __shared__ float kbuf[2][4096];
  __shared__ float part[4][16][12];
  const int tid = threadIdx.x;
  const int lane = tid & 63, w = tid >> 6;
  const int r = lane & 15, q = lane >> 4;
  const int head = blockIdx.x >> 7, rb = blockIdx.x & 127;
  const int row = rb*16 + r;
  const float* qp = qkv + (size_t)row*288 + head*8;
  float4 qa = *(const float4*)qp;
  float4 qb = *(const float4*)(qp + 4);
  const float* base = kvp + (size_t)head*32768;
  float4 st0 = *(const float4*)(base + tid*4);
  float4 st1 = *(const float4*)(base + 1024 + tid*4);
  float4 st2 = *(const float4*)(base + 2048 + tid*4);
  float4 st3 = *(const float4*)(base + 3072 + tid*4);
  *(float4*)&kbuf[0][tid*4]        = st0;
  *(float4*)&kbuf[0][1024 + tid*4] = st1;
  *(float4*)&kbuf[0][2048 + tid*4] = st2;
  *(float4*)&kbuf[0][3072 + tid*4] = st3;
  __syncthreads();
  float sm = 0.f;
  float o0=0,o1=0,o2=0,o3=0,o4=0,o5=0,o6=0,o7=0;
  for (int c = 0; c < 8; c++){
    if (c < 7){
      const float* nb = base + (c+1)*4096;
      st0 = *(const float4*)(nb + tid*4);
      st1 = *(const float4*)(nb + 1024 + tid*4);
      st2 = *(const float4*)(nb + 2048 + tid*4);
      st3 = *(const float4*)(nb + 3072 + tid*4);
    }
    const float* kp0 = &kbuf[c & 1][(w*64 + q)*16];
    #pragma unroll
    for (int i = 0; i < 16; i++){
      const float* kp = kp0 + i*64;
      float4 ka = *(const float4*)kp;
      float4 kb4 = *(const float4*)(kp + 4);
      float4 va = *(const float4*)(kp + 8);
      float4 vb = *(const float4*)(kp + 12);
      float s = qa.x*ka.x + qa.y*ka.y + qa.z*ka.z + qa.w*ka.w
              + qb.x*kb4.x + qb.y*kb4.y + qb.z*kb4.z + qb.w*kb4.w;
      s = fminf(s * 0.35355339059327373f, 60.f);
      float p = __expf(s);
      sm += p;
      o0 += p*va.x; o1 += p*va.y; o2 += p*va.z; o3 += p*va.w;
      o4 += p*vb.x; o5 += p*vb.y; o6 += p*vb.z; o7 += p*vb.w;
    }
    if (c < 7){
      float* wb = kbuf[(c+1) & 1];
      *(float4*)&wb[tid*4]        = st0;
      *(float4*)&wb[1024 + tid*4] = st1;
      *(float4*)&wb[2048 + tid*4] = st2;
      *(float4*)&wb[3072 + tid*4] = st3;
      __syncthreads();
    }
  }
  #pragma unroll
  for (int stx = 16; stx < 64; stx <<= 1){
    o0 += __shfl_xor(o0, stx); o1 += __shfl_xor(o1, stx);
    o2 += __shfl_xor(o2, stx); o3 += __shfl_xor(o3, stx);
    o4 += __shfl_xor(o4, stx); o5 += __shfl_xor(o5, stx);
    o6 += __shfl_xor(o6, stx); o7 += __shfl_xor(o7, stx);
    sm += __shfl_xor(sm, stx);
  }
  if (q == 0){
    float* pp = part[w][r];
    pp[0]=o0; pp[1]=o1; pp[2]=o2; pp[3]=o3; pp[4]=o4; pp[5]=o5; pp[6]=o6; pp[7]=o7; pp[8]=sm;
  }
  __syncthreads();
  if (tid < 128){
    int rr = tid >> 3, d = tid & 7;
    float o  = part[0][rr][d] + part[1][rr][d] + part[2][rr][d] + part[3][rr][d];
    float ss = part[0][rr][8] + part[1][rr][8] + part[2][rr][8] + part[3][rr][8];
    obuf[(size_t)(rb*16 + rr)*96 + head*8 + d] = o / ss;
  }
}

// ---------------- fused edge MLPs (packed weights from L2) ----------------
__global__ __launch_bounds__(256) void k_edge(const float* __restrict__ efr, const float* __restrict__ es,
    const u16* __restrict__ pk,
    const float* __restrict__ eb1, const float* __restrict__ eb2,
    const float* __restrict__ adb1, const float* __restrict__ adw2, const float* __restrict__ adb2,
    const float* __restrict__ arb1, const float* __restrict__ arw2, const float* __restrict__ arb2,
    u16* __restrict__ efnn, float* __restrict__ alpha)
{
  __shared__ __align__(16) char smem[16384];
  const int tid = threadIdx.x;
  const int e0 = blockIdx.x * 64;
  for (int j = tid; j < 64*16; j += 256){
    int r = j >> 4; int c = (j & 15) * 2;
    float f0 = 0.f, f1 = 0.f;
    if (c < 12)     f0 = (efr[(size_t)(e0+r)*12 + c]     + 1e-4f) / es[c];
    if (c + 1 < 12) f1 = (efr[(size_t)(e0+r)*12 + c + 1] + 1e-4f) / es[c+1];
    *(u32*)(smem + swzb(r*128 + c*2, r)) = (u32)f2bf(f0) | ((u32)f2bf(f1) << 16);
  }
  __syncthreads();
  const int lane = tid & 63, w = tid >> 6;
  const int r15 = lane & 15;

  auto store_lds = [&](f32x4* acc, int base, const float* bias){
    #pragma unroll
    for (int ct = 0; ct < 4; ct++){
      int col = ct*16 + r15;
      float bs = bias[col];
      #pragma unroll
      for (int q = 0; q < 4; q++){
        int row = w*16 + (lane >> 4)*4 + q;
        *(u16*)(smem + base + swzb(row*128 + col*2, row)) = f2bf(lrelu(acc[ct][q] + bs));
      }
    }
  };

  { f32x4 acc[4] = {};
    tile_gemm_gp<4,1,128,4>(smem, w*2048, pk + PK_EIN1, lane, acc);
    store_lds(acc, 8192, eb1); }
  __syncthreads();
  { f32x4 acc[4] = {};
    tile_gemm_gp<4,2,128,4>(smem, 8192 + w*2048, pk + PK_EIN2, lane, acc);
    store_lds(acc, 0, eb2); }
  __syncthreads();
  for (int j = tid; j < 2048; j += 256){
    int r = j >> 5;
    ((u32*)efnn)[e0*32 + j] = *(const u32*)(smem + swzb(r*128 + (j&31)*4, r));
  }
  { f32x4 acc[4] = {};
    tile_gemm_gp<4,2,128,4>(smem, w*2048, pk + PK_AD1, lane, acc);
    store_lds(acc, 8192, adb1); }
  __syncthreads();
  { int row = tid >> 2, part = tid & 3;
    float s = 0.f;
    #pragma unroll
    for (int i = 0; i < 16; i++){
      int k = part*16 + i;
      s += bf2f(*(const u16*)(smem + 8192 + swzb(row*128 + k*2, row))) * adw2[k];
    }
    s += __shfl_xor(s, 1); s += __shfl_xor(s, 2);
    if (part == 0) alpha[e0 + row] = 1.f / (1.f + __expf(-(s + adb2[0]))); }
  __syncthreads();
  { f32x4 acc[4] = {};
    tile_gemm_gp<4,2,128,4>(smem, w*2048, pk + PK_AR1, lane, acc);
    store_lds(acc, 8192, arb1); }
  __syncthreads();
  { int row = tid >> 2, part = tid & 3;
    float s = 0.f;
    #pragma unroll
    for (int i = 0; i < 16; i++){
      int k = part*16 + i;
      s += bf2f(*(const u16*)(smem + 8192 + swzb(row*128 + k*2, row))) * arw2[k];
    }
    s += __shfl_xor(s, 1); s += __shfl_xor(s, 2);
    if (part == 0) alpha[EE + e0 + row] = 1.f / (1.f + __expf(-(s + arb2[0]))); }
}

// ---------------- graph-conv v8: gc5x body, 2 blocks/node (chunks strided), atomic num --------
// P[N][384] = [P1|P2] with GC_B1 folded into p1c at init. Meta packed (i2, alpha).
// (Measured optimum: 2-way split; 1-way=70, 4-way=90, dbuf=85, reg-A=121 — R10..R17 ladder.)
__global__ __launch_bounds__(256) void k_gc8(const float* __restrict__ P,
    const int2* __restrict__ meta, const int* __restrict__ offs,
    const u16* __restrict__ wt2p, const float* __restrict__ b1, const float* __restrict__ b2,
    float* __restrict__ num)
{
  __shared__ __align__(16) char smem[26624];
  float* p1c  = (float*)(smem + 24576);
  int*   i2b  = (int*)  (smem + 25344);
  float* alph = (float*)(smem + 25600);
  float* part = (float*)(smem + 25856);
  const int tid = threadIdx.x;
  const int lane = tid & 63, w = tid >> 6;
  const int wr = w >> 1, wc = w & 1;
  const int r15 = lane & 15;
  const int kb = (lane >> 4) * 16;
  const int n = blockIdx.x >> 1, sp = blockIdx.x & 1;
  const int rbeg = offs[n], rend = offs[n + 1];
  if (tid < 192) p1c[tid] = P[(size_t)n*384 + tid] + b1[tid];
  float b2r[3];
  #pragma unroll
  for (int ct = 0; ct < 3; ct++) b2r[ct] = b2[wc*48 + ct*16 + r15];
  float cs0 = 0.f, cs1 = 0.f, cs2 = 0.f;

  const int total = rend - rbeg + (n == 0 ? 1 : 0);   // node 0: +1 virtual row
  const int nch = (total + 63) >> 6;

  int pm_i2 = 0; float pm_al = 0.f;
  auto fetch_meta = [&](int c){
    if (tid < 64){
      int pos = rbeg + c*64 + tid;
      if (pos < rend){
        int2 v = meta[pos];
        pm_i2 = v.x;
        pm_al = __int_as_float(v.y);
      } else if (n == 0 && pos == rend){ pm_i2 = 0; pm_al = 2048.f; }
      else { pm_i2 = 0; pm_al = 0.f; }
    }
  };
  fetch_meta(sp);
  __syncthreads();   // p1c visible
  for (int c = sp; c < nch; c += 2){
    if (tid < 64){ i2b[tid] = pm_i2; alph[tid] = pm_al; }
    __syncthreads();
    for (int j = tid; j < 1536; j += 256){
      int r = j / 24, q = j - (j/24)*24;
      int c8 = q * 8;
      const float* p2 = P + (size_t)i2b[r]*384 + 192 + c8;
      float4 b0 = *(const float4*)p2, b1v = *(const float4*)(p2 + 4);
      const float* pc = p1c + c8;
      u16 pkv[8];
      pkv[0]=f2bf(lrelu(pc[0]+b0.x)); pkv[1]=f2bf(lrelu(pc[1]+b0.y));
      pkv[2]=f2bf(lrelu(pc[2]+b0.z)); pkv[3]=f2bf(lrelu(pc[3]+b0.w));
      pkv[4]=f2bf(lrelu(pc[4]+b1v.x)); pkv[5]=f2bf(lrelu(pc[5]+b1v.y));
      pkv[6]=f2bf(lrelu(pc[6]+b1v.z)); pkv[7]=f2bf(lrelu(pc[7]+b1v.w));
      *(bf16x8*)(smem + swzb(r*384 + c8*2, r)) = *(bf16x8*)pkv;
    }
    __syncthreads();
    float ar[2][4];
    #pragma unroll
    for (int rt = 0; rt < 2; rt++)
      #pragma unroll
      for (int q = 0; q < 4; q++)
        ar[rt][q] = alph[wr*32 + rt*16 + (lane >> 4)*4 + q];
    if (c + 2 < nch) fetch_meta(c + 2);        // overlaps MFMA below
    f32x4 acc2[2][3] = {};
    #pragma unroll
    for (int ks = 0; ks < 6; ks++){
      bf16x8 a[2];
      #pragma unroll
      for (int rt = 0; rt < 2; rt++){
        int row = wr*32 + rt*16 + r15;
        a[rt] = *(const bf16x8*)(smem + swzb(row*384 + ks*64 + kb, row));
      }
      #pragma unroll
      for (int ct = 0; ct < 3; ct++){
        bf16x8 b = *(const bf16x8*)(wt2p + (((size_t)ks*6 + wc*3 + ct)*64 + lane)*8);
        #pragma unroll
        for (int rt = 0; rt < 2; rt++)
          acc2[rt][ct] = __builtin_amdgcn_mfma_f32_16x16x32_bf16(a[rt], b, acc2[rt][ct], 0, 0, 0);
      }
    }
    #pragma unroll
    for (int rt = 0; rt < 2; rt++){
      #pragma unroll
      for (int q = 0; q < 4; q++){
        float aw = ar[rt][q];
        cs0 += aw * lrelu(acc2[rt][0][q] + b2r[0]);
        cs1 += aw * lrelu(acc2[rt][1][q] + b2r[1]);
        cs2 += aw * lrelu(acc2[rt][2][q] + b2r[2]);
      }
    }
    __syncthreads();
  }
  #pragma unroll
  for (int stx = 16; stx < 64; stx <<= 1){
    cs0 += __shfl_xor(cs0, stx);
    cs1 += __shfl_xor(cs1, stx);
    cs2 += __shfl_xor(cs2, stx);
  }
  if (lane < 16){
    part[(w*3 + 0)*16 + lane] = cs0;
    part[(w*3 + 1)*16 + lane] = cs1;
    part[(w*3 + 2)*16 + lane] = cs2;
  }
  __syncthreads();
  if (tid < 96){
    int wc2 = tid / 48, rem = tid - wc2*48;
    int ct = rem / 16, rr = rem - ct*16;
    float tot = part[(wc2*3 + ct)*16 + rr] + part[((2 + wc2)*3 + ct)*16 + rr];
    atomicAdd(num + (size_t)n*96 + tid, tot);
  }
}

// ---------------- final predictor v3: hp[N][192] combined, EN_B1 here ----------------
__global__ __launch_bounds__(256) void k_final3(const float* __restrict__ hp,
    const int* __restrict__ ei, const u16* __restrict__ efnn, const float* __restrict__ efr,
    const float* __restrict__ es, const u16* __restrict__ encp, const float* __restrict__ enb1,
    const float* __restrict__ enw2, const float* __restrict__ enb2, float* __restrict__ out)
{
  __shared__ __align__(16) char smem[38400];
  float* etb = (float*)(smem + 12288);
  float* w2s = (float*)(smem + 37120);
  float* b1s = (float*)(smem + 37504);
  int*   eix = (int*)  (smem + 37888);
  const int tid = threadIdx.x;
  const int e0 = blockIdx.x * 64;
  for (int j = tid; j < 768; j += 256){
    int r = j / 12, q = j - (j/12)*12;
    int e = e0 + r;
    bf16x8 v;
    if (q < 8){
      v = *(const bf16x8*)(efnn + (size_t)e*64 + q*8);
    } else if (q < 10){
      u16 pkv[8];
      #pragma unroll
      for (int i = 0; i < 8; i++){
        int cc = (q - 8)*8 + i;
        pkv[i] = (cc < 12) ? f2bf((efr[(size_t)e*12 + cc] + 1e-4f) / es[cc]) : (u16)0;
      }
      v = *(bf16x8*)pkv;
    } else {
      v = bf16x8{0,0,0,0,0,0,0,0};
    }
    *(bf16x8*)(smem + swzb(r*192 + q*16, r)) = v;
  }
  if (tid < 96) w2s[tid] = enw2[tid];
  else if (tid < 192) b1s[tid - 96] = enb1[tid - 96];
  if (tid < 64){ eix[2*tid] = ei[2*(e0+tid)]; eix[2*tid+1] = ei[2*(e0+tid)+1]; }
  __syncthreads();
  const int lane = tid & 63, w = tid >> 6;
  const int r15 = lane & 15;
  f32x4 acc[6] = {};
  tile_gemm_gp<6,3,192,6>(smem, w*16*192, encp, lane, acc);
  #pragma unroll
  for (int ct = 0; ct < 6; ct++){
    int col = ct*16 + r15;
    #pragma unroll
    for (int q = 0; q < 4; q++){
      int row = w*16 + (lane >> 4)*4 + q;
      etb[row*97 + col] = acc[ct][q];
    }
  }
  __syncthreads();
  int r = tid >> 2, part = tid & 3;
  int s1 = eix[2*r], s2 = eix[2*r + 1];
  const float* p1 = hp + (size_t)s1*192 + part*24;
  const float* p2 = hp + (size_t)s2*192 + 96 + part*24;
  const float* et = etb + r*97 + part*24;
  const float* wz = w2s + part*24;
  const float* bz = b1s + part*24;
  float s = 0.f;
  #pragma unroll
  for (int i = 0; i < 24; i++){
    float v = et[i] + p1[i] + p2[i] + bz[i];
    s += lrelu(v) * wz[i];
  }
  s += __shfl_xor(s, 1); s += __shfl_xor(s, 2);
  if (part == 0) out[e0 + r] = 1.f / (1.f + __expf(-(s + enb2[0])));
}

// ---------------- host ----------------
extern "C" void kernel_launch(void* const* d_in, const int* in_sizes, int n_in,
                              void* d_out, int out_size, void* d_ws, size_t ws_size,
                              hipStream_t stream) {
  (void)in_sizes; (void)n_in; (void)out_size; (void)ws_size;
  const float* X      = (const float*)d_in[0];
  const float* EFR    = (const float*)d_in[1];
  const int*   EI     = (const int*)  d_in[2];
  const float* NS     = (const float*)d_in[3];
  const float* ES     = (const float*)d_in[4];
  const float* IN_W1  = (const float*)d_in[5];
  const float* IN_B1  = (const float*)d_in[6];
  const float* IN_W2  = (const float*)d_in[7];
  const float* IN_B2  = (const float*)d_in[8];
  const float* QKV_W  = (const float*)d_in[9];
  const float* QKV_B  = (const float*)d_in[10];
  const float* OUT_W  = (const float*)d_in[11];
  const float* OUT_B  = (const float*)d_in[12];
  const float* LN1S   = (const float*)d_in[13];
  const float* LN1B   = (const float*)d_in[14];
  const float* FFW1   = (const float*)d_in[15];
  const float* FFB1   = (const float*)d_in[16];
  const float* FFW2   = (const float*)d_in[17];
  const float* FFB2   = (const float*)d_in[18];
  const float* LN2S   = (const float*)d_in[19];
  const float* LN2B   = (const float*)d_in[20];
  const float* EIN_W1 = (const float*)d_in[21];
  const float* EIN_B1 = (const float*)d_in[22];
  const float* EIN_W2 = (const float*)d_in[23];
  const float* EIN_B2 = (const float*)d_in[24];
  const float* AD_W1  = (const float*)d_in[25];
  const float* AD_B1  = (const float*)d_in[26];
  const float* AD_W2  = (const float*)d_in[27];
  const float* AD_B2  = (const float*)d_in[28];
  const float* AR_W1  = (const float*)d_in[29];
  const float* AR_B1  = (const float*)d_in[30];
  const float* AR_W2  = (const float*)d_in[31];
  const float* AR_B2  = (const float*)d_in[32];
  const float* GC_W1  = (const float*)d_in[33];
  const float* GC_B1  = (const float*)d_in[34];
  const float* GC_W2  = (const float*)d_in[35];
  const float* GC_B2  = (const float*)d_in[36];
  const float* EN_W1  = (const float*)d_in[37];
  const float* EN_B1  = (const float*)d_in[38];
  const float* EN_W2  = (const float*)d_in[39];
  const float* EN_B2  = (const float*)d_in[40];

  char* ws = (char*)d_ws;
  u16*   pool   = (u16*)  (ws + WS_WT);
  u16*   efnn   = (u16*)  (ws + WS_EFNN);
  float* alpha  = (float*)(ws + WS_ALPHA);
  float* h      = (float*)(ws + WS_H);
  float* qkvb   = (float*)(ws + WS_QKV);
  float* obuf   = (float*)(ws + WS_OBUF);
  float* tmpA   = (float*)(ws + WS_TMPA);
  float* tmpB   = (float*)(ws + WS_TMPB);
  float* x1     = (float*)(ws + WS_X1);
  float* num    = (float*)(ws + WS_NUM);
  float* den    = (float*)(ws + WS_DEN);
  float* xs     = (float*)(ws + WS_XS);
  int2*  meta   = (int2*) (ws + WS_META);
  int*   cnt    = (int*)  (ws + WS_CNT);
  int*   offs   = (int*)  (ws + WS_OFFS);
  u16*   pk     = (u16*)  (ws + WS_PK);
  float* P      = (float*)(ws + WS_QKV);   // [N][384], spans QKV+OBUF (dead after encoder)
  float* hp     = (float*)(ws + WS_TMPB);  // [N][192]
  float* kvp    = (float*)(ws + WS_ALPHA); // reuse: alpha dead after k_scatter

  // ---- weight conversion jobs ----
  CvtJobs jb;
  int idx = 0, cum = 0;
  auto addjob = [&](const float* s, int K, int Nc, int Kp){
    jb.src[idx] = s; jb.K[idx] = K; jb.Nc[idx] = Nc; jb.Kp[idx] = Kp;
    jb.cum[idx] = cum; cum += Nc * Kp; idx++;
  };
  addjob(IN_W1, 19, 96, 32);
  addjob(IN_W2, 96, 96, 96);
  for (int l = 0; l < 3; l++) addjob(QKV_W + (size_t)l*96*288, 96, 288, 96);
  for (int l = 0; l < 3; l++) addjob(OUT_W + (size_t)l*96*96,  96, 96,  96);
  for (int l = 0; l < 3; l++) addjob(FFW1  + (size_t)l*96*192, 96, 192, 96);
  for (int l = 0; l < 3; l++) addjob(FFW2  + (size_t)l*192*96, 192, 96, 192);
  addjob(EIN_W1, 12, 64, 32);
  addjob(EIN_W2, 64, 64, 64);
  addjob(AD_W1,  64, 64, 64);
  addjob(AR_W1,  64, 64, 64);
  for (int i = 0; i < 2; i++){
    addjob(GC_W1 + (size_t)i*192*192,          96, 192, 96);
    addjob(GC_W1 + (size_t)i*192*192 + 96*192, 96, 192, 96);
  }
  for (int i = 0; i < 2; i++) addjob(GC_W2 + (size_t)i*192*96, 192, 96, 192);
  addjob(EN_W1,            96, 96, 96);
  addjob(EN_W1 + 96*96,    96, 96, 96);
  addjob(EN_W1 + 192*96,   76, 96, 96);
  jb.cum[idx] = cum;

  k_cvt<<<(POOL_TOT + 255)/256, 256, 0, stream>>>(jb, pool);

  // ---- fragment packing jobs; ORDER MUST MATCH PK_* offsets ----
  PkJobs pj;
  int pidx = 0, pcum = 0;
  auto addpk = [&](int srcOff, int Nc16, int Ks, int Kp){
    pj.srcOff[pidx] = srcOff; pj.Nc16[pidx] = Nc16; pj.Kp[pidx] = Kp;
    pj.cum[pidx] = pcum; pcum += Nc16 * Ks * 512; pidx++;
  };
  addpk(EIN1T, 4, 1, 32);
  addpk(EIN2T, 4, 2, 64);
  addpk(AD1T,  4, 2, 64);
  addpk(AR1T,  4, 2, 64);
  addpk(GC2T,          6, 6, 192);
  addpk(GC2T + 18432,  6, 6, 192);
  addpk(ENCT, 6, 3, 96);
  for (int l = 0; l < 3; l++) addpk(QKVT + l*27648, 18, 3, 96);
  for (int l = 0; l < 3; l++) addpk(OUTT + l*9216,   6, 3, 96);
  for (int l = 0; l < 3; l++) addpk(FF1T + l*18432, 12, 3, 96);
  for (int l = 0; l < 3; l++) addpk(FF2T + l*18432,  6, 6, 192);
  addpk(IN1T, 6, 1, 32);
  addpk(IN2T, 6, 3, 96);
  for (int i = 0; i < 2; i++) addpk(GC1T + i*36864, 24, 3, 96);   // A|B combined
  addpk(ENAT, 12, 3, 96);                                        // ENA|ENB combined
  for (int z = pidx; z <= 27; z++) pj.cum[z] = pcum;              // == PK_TOT

  k_pack<<<(PK_TOT + 255)/256, 256, 0, stream>>>(pj, pool, pk);

  // ---- node embedding ----
  k_xscale<<<(NN*19 + 255)/256, 256, 0, stream>>>(X, NS, xs);
  k_gemm2<3,1,0,1><<<dim3(64,1), 256, 0, stream>>>(xs, 19, 96, 6, pk + PK_IN1, IN_B1, tmpA,
                                                   nullptr, nullptr, nullptr, nullptr, nullptr);
  k_gemm2<3,3,0,1><<<dim3(64,1), 256, 0, stream>>>(tmpA, 96, 96, 6, pk + PK_IN2, IN_B2, h,
                                                   nullptr, nullptr, nullptr, nullptr, nullptr);

  // ---- edge MLPs + attention weights ----
  k_edge<<<EE/64, 256, 0, stream>>>(EFR, ES, pk, EIN_B1, EIN_B2,
                                    AD_B1, AD_W2, AD_B2, AR_B1, AR_W2, AR_B2, efnn, alpha);

  // ---- destination sort + den ----
  (void)hipMemsetAsync(cnt, 0, NN*4, stream);
  k_hist<<<(2*EE)/256, 256, 0, stream>>>(EI, cnt);
  k_scan<<<1, 256, 0, stream>>>(cnt, offs);
  (void)hipMemsetAsync(cnt, 0, NN*4, stream);
  k_scatter<<<(2*EE)/256, 256, 0, stream>>>(EI, alpha, offs, cnt, meta);
  k_dens<<<NN/4, 256, 0, stream>>>(offs, meta, den);

  // ---- 3 encoder layers (5 launches each) ----
  for (int l = 0; l < 3; l++){
    k_gemm2<3,3,1,0><<<dim3(64,3), 256, 0, stream>>>(h, 96, 288, 18, pk + PK_QKV + l*27648,
                                                     QKV_B + l*288, qkvb, kvp, nullptr, nullptr, nullptr, nullptr);
    k_attn5<<<1536, 256, 0, stream>>>(qkvb, kvp, obuf);
    k_gemm2<3,3,2,0><<<dim3(64,1), 256, 0, stream>>>(obuf, 96, 96, 6, pk + PK_OUT + l*9216,
                                                     OUT_B + l*96, x1, nullptr, h, LN1S + l*96, LN1B + l*96, nullptr);
    k_gemm2<3,3,0,2><<<dim3(64,2), 256, 0, stream>>>(x1, 96, 192, 12, pk + PK_FF1 + l*18432,
                                                     FFB1 + l*192, tmpB, nullptr, nullptr, nullptr, nullptr, nullptr);
    k_gemm2<3,6,2,0><<<dim3(64,1), 256, 0, stream>>>(tmpB, 192, 96, 6, pk + PK_FF2 + l*18432,
                                                     FFB2 + l*96, h, nullptr, x1, LN2S + l*96, LN2B + l*96, nullptr);
  }

  // ---- 2 graph-conv iterations: P = [h@W1a | h@W1b] (one gemm), 2-way split gc, atomic num ----
  for (int it = 0; it < 2; it++){
    if (it == 0){
      k_gemm2<3,3,0,0><<<dim3(64,3), 256, 0, stream>>>(h, 96, 384, 24, pk + PK_GC1 + it*36864,
                                                       nullptr, P, nullptr, nullptr, nullptr, nullptr, nullptr);
    } else {
      k_gemm2<3,3,0,0,1><<<dim3(64,3), 256, 0, stream>>>(num, 96, 384, 24, pk + PK_GC1 + it*36864,
                                                         nullptr, P, nullptr, nullptr, nullptr, nullptr, den);
    }
    (void)hipMemsetAsync(num, 0, NN*96*4, stream);
    k_gc8<<<2*NN, 256, 0, stream>>>(P, meta, offs,
                                    pk + PK_GC2 + it*18432, GC_B1 + it*192, GC_B2 + it*96, num);
  }

  // ---- final predictor: hp = [num/den @ ENA | @ ENB] (one gemm, no bias) ----
  k_gemm2<3,3,0,0,1><<<dim3(64,2), 256, 0, stream>>>(num, 96, 192, 12, pk + PK_ENAB,
                                                     nullptr, hp, nullptr, nullptr, nullptr, nullptr, den);
  k_final3<<<EE/64, 256, 0, stream>>>(hp, EI, efnn, EFR, ES,
                                      pk + PK_ENC, EN_B1, EN_W2, EN_B2, (float*)d_out);
}